// Round 1
// baseline (865.599 us; speedup 1.0000x reference)
//
#include <hip/hip_runtime.h>
#include <cstddef>

// EfficientAttention pipeline, MI355X. fp32 throughout.
// B=64, DIM=128, N=4000, H=4, DH=32, CL=50, K=9.
// R4: fused embed1/embed2/softmax-free cluster_x kernel (exp factorization:
// cx = (x @ exp(E1)^T) / Z, Z from a ones-row). All GEMM-ish kernels use 2D
// register tiles with b128 LDS reads; no s_load chains, no broadcast-b32 storms.

// ---- workspace offsets (in floats) ----
constexpr size_t O_MU    = 0;                   // 8192
constexpr size_t O_RINV  = 8192;                // 8192
constexpr size_t O_RATIO = 16384;               // 8192
constexpr size_t O_A1    = 24576;               // 128
constexpr size_t O_B1    = 24704;
constexpr size_t O_A2    = 24832;
constexpr size_t O_B2    = 24960;
constexpr size_t O_PROJWT= 25088;               // 128x128 proj_w^T [d][o]
constexpr size_t O_VPROJ = 41472;               // 128  projw@pres_b
constexpr size_t O_MT    = 41600;               // 256x128  M^T [k][o], M=projw@presw
constexpr size_t O_E2    = 74368;               // 64*50*4000
constexpr size_t O_UCXP  = 12874368;            // 8*64*132*56 fused GEMM partials
constexpr size_t O_CX    = 16659072;            // 64*128*50 [b][d][c]
constexpr size_t O_XT    = 17068672;            // 64*4*50*32 [b][h][c][d]
constexpr size_t O_QT    = 17478272;
constexpr size_t O_KT    = 17887872;
constexpr size_t O_VT    = 18297472;
constexpr size_t O_H1    = 18707072;            // 64*4*150*32
constexpr size_t O_P1    = 19935872;            // 64*256
constexpr size_t O_BN1S  = 19952256;            // 128
constexpr size_t O_BN1T  = 19952384;
constexpr size_t O_H2    = 19952512;            // 64*4*50*32
constexpr size_t O_P2    = 20362112;            // 256*64
constexpr size_t O_BN2S  = 20378496;
constexpr size_t O_BN2T  = 20378624;
constexpr size_t O_CAT   = 20378752;            // 64*256*50 [b][ch][n]
constexpr size_t O_PRES2 = 21197952;            // 64*50*128 [b][c][o]

// ---------------- K1: per-(b,c) instance-norm stats over n=4000 ----------------
__global__ __launch_bounds__(256) void k_rowstats(const float* __restrict__ x,
                                                  float* __restrict__ ws){
  int row = blockIdx.x;                       // b*128+c
  const float4* xr = (const float4*)(x + (size_t)row * 4000);
  float s = 0.f, sq = 0.f;
  for(int i = threadIdx.x; i < 1000; i += 256){
    float4 v = xr[i];
    s  += v.x + v.y + v.z + v.w;
    sq += v.x*v.x + v.y*v.y + v.z*v.z + v.w*v.w;
  }
  __shared__ float ls[256], lq[256];
  ls[threadIdx.x] = s; lq[threadIdx.x] = sq; __syncthreads();
  for(int st = 128; st > 0; st >>= 1){
    if(threadIdx.x < st){ ls[threadIdx.x] += ls[threadIdx.x+st]; lq[threadIdx.x] += lq[threadIdx.x+st]; }
    __syncthreads();
  }
  if(threadIdx.x == 0){
    float mean = ls[0] * (1.f/4000.f);
    float var  = lq[0] * (1.f/4000.f) - mean*mean;
    ws[O_MU   + row] = mean;
    ws[O_RINV + row] = rsqrtf(var + 1e-3f);
    ws[O_RATIO+ row] = var / (var + 1e-3f);
  }
}

// ---------------- K2: BN stats (mu2==0 exactly) + small weight prep ----------------
__global__ void k_prep(const float* g1g, const float* g1b,
                       const float* g2g, const float* g2b,
                       const float* presb, const float* projw,
                       float* __restrict__ ws){
  int t = threadIdx.x;
  if(t < 128){
    float s = 0.f;
    for(int b = 0; b < 64; b++) s += ws[O_RATIO + b*128 + t];
    float var2 = s * (1.f/64.f);
    float inv2 = rsqrtf(var2 + 1e-5f);
    ws[O_A1+t] = g1g[t] * inv2;  ws[O_B1+t] = g1b[t];
    ws[O_A2+t] = g2g[t] * inv2;  ws[O_B2+t] = g2b[t];
  }
  for(int i = t; i < 16384; i += 256){ int o = i & 127, k = i >> 7; ws[O_PROJWT+i] = projw[o*128 + k]; }
  __syncthreads();
  if(t < 128){
    float v = 0.f;
    for(int d = 0; d < 128; d++) v += ws[O_PROJWT + d*128 + t] * presb[d];
    ws[O_VPROJ + t] = v;
  }
}

// ---------------- K2b: M^T[k][o] = sum_d projw^T[d][o] * presw[d][k] ----------------
__global__ __launch_bounds__(256) void k_mprep(const float* __restrict__ presw,
                                               float* __restrict__ ws){
  int kk2 = blockIdx.x * 2;                   // 128 blocks
  __shared__ float pwc[2][128];
  int t = threadIdx.x;
  { int which = t >> 7, d = t & 127; pwc[which][d] = presw[d*256 + kk2 + which]; }
  __syncthreads();
  int which = t >> 7, o = t & 127;
  float acc = 0.f;
  for(int d = 0; d < 128; d++) acc += ws[O_PROJWT + d*128 + o] * pwc[which][d];
  ws[O_MT + (size_t)(kk2 + which)*128 + o] = acc;
}

// ---------------- K3: fused embed1/embed2 + exp + unnormalized cluster GEMM ----------------
// grid (8 ch, 64 b), 256 thr. Per block: n-chunk of 500 (8 subtiles of 64, last 52).
__global__ __launch_bounds__(256) void k_fused(const float* __restrict__ x,
    const float* __restrict__ wg1, const float* __restrict__ bg1,
    const float* __restrict__ wg2, const float* __restrict__ bg2,
    float* __restrict__ ws){
  int ch = blockIdx.x, b = blockIdx.y;
  __shared__ float lW1[128*56];     // [c][cl], cl padded 56 (zeros)
  __shared__ float lW2[128*56];
  __shared__ float lrv1[128*64];    // [c][j]; after E1: eU overlay [56][64]
  __shared__ float lrv2[128*64];
  __shared__ float lxt [64*132];    // [n][d], d 0..127 + ones-row 128 (+pad)
  __shared__ float ca1[128], cb1[128], ca2[128], cb2[128];
  __shared__ float bg1p[64], bg2p[64];
  int t = threadIdx.x;
  // one-time stages
  if(t < 128){
    float mu = ws[O_MU + b*128 + t], ri = ws[O_RINV + b*128 + t];
    float a1 = ws[O_A1+t]*ri, a2 = ws[O_A2+t]*ri;
    ca1[t] = a1; cb1[t] = ws[O_B1+t] - a1*mu;
    ca2[t] = a2; cb2[t] = ws[O_B2+t] - a2*mu;
  }
  if(t < 64){ bg1p[t] = (t < 50) ? bg1[t] : 0.f; bg2p[t] = (t < 50) ? bg2[t] : 0.f; }
  for(int i = t; i < 1600; i += 256){         // 50 cl rows x 32 float4 over c
    int cl = i >> 5, cq = i & 31;
    float4 w1 = *(const float4*)&wg1[cl*128 + cq*4];
    float4 w2 = *(const float4*)&wg2[cl*128 + cq*4];
    int c0 = cq*4;
    lW1[(c0+0)*56+cl] = w1.x; lW1[(c0+1)*56+cl] = w1.y; lW1[(c0+2)*56+cl] = w1.z; lW1[(c0+3)*56+cl] = w1.w;
    lW2[(c0+0)*56+cl] = w2.x; lW2[(c0+1)*56+cl] = w2.y; lW2[(c0+2)*56+cl] = w2.z; lW2[(c0+3)*56+cl] = w2.w;
  }
  for(int i = t; i < 768; i += 256){          // zero cl pads 50..55
    int cl = 50 + i/128, c = i%128;
    lW1[c*56+cl] = 0.f; lW2[c*56+cl] = 0.f;
  }
  // persistent UCX accumulators: thread (dg 0..32, cg 0..6), d=dg*4, c=cg*8
  int dg = t % 33, cg = t / 33;               // valid when t < 231
  float ua[4][8];
  #pragma unroll
  for(int r = 0; r < 4; r++)
    #pragma unroll
    for(int i = 0; i < 8; i++) ua[r][i] = 0.f;
  int ig = t >> 4, jg = t & 15;
  int clb = ig*4, j4 = jg*4;
  float e[4][4];

  for(int st = 0; st < 8; st++){
    int nb = ch*500 + st*64;
    int lim = (st == 7) ? 52 : 64;
    __syncthreads();
    // stage x tile: lxt[n][d] raw (+zeros pad), lrv1/lrv2 = relu(affine)
    for(int i = t; i < 2048; i += 256){
      int c = i >> 4, jj = (i & 15)*4;
      float4 xv = make_float4(0.f,0.f,0.f,0.f);
      if(jj < lim) xv = *(const float4*)&x[(size_t)(b*128 + c)*4000 + nb + jj];
      lxt[(jj+0)*132 + c] = xv.x; lxt[(jj+1)*132 + c] = xv.y;
      lxt[(jj+2)*132 + c] = xv.z; lxt[(jj+3)*132 + c] = xv.w;
      float a1 = ca1[c], b1v = cb1[c], a2 = ca2[c], b2v = cb2[c];
      float4 r1, r2;
      r1.x = fmaxf(a1*xv.x + b1v, 0.f); r1.y = fmaxf(a1*xv.y + b1v, 0.f);
      r1.z = fmaxf(a1*xv.z + b1v, 0.f); r1.w = fmaxf(a1*xv.w + b1v, 0.f);
      r2.x = fmaxf(a2*xv.x + b2v, 0.f); r2.y = fmaxf(a2*xv.y + b2v, 0.f);
      r2.z = fmaxf(a2*xv.z + b2v, 0.f); r2.w = fmaxf(a2*xv.w + b2v, 0.f);
      *(float4*)&lrv1[c*64 + jj] = r1;
      *(float4*)&lrv2[c*64 + jj] = r2;
    }
    if(t < 64){
      lxt[t*132 + 128] = (t < lim) ? 1.f : 0.f;   // ones-row -> Z
      lxt[t*132 + 129] = 0.f; lxt[t*132 + 130] = 0.f; lxt[t*132 + 131] = 0.f;
    }
    __syncthreads();
    // E1 GEMM: rows 56 (ig<14) x cols 64
    if(ig < 14){
      #pragma unroll
      for(int r = 0; r < 4; r++){ e[r][0]=0.f; e[r][1]=0.f; e[r][2]=0.f; e[r][3]=0.f; }
      #pragma unroll 4
      for(int c = 0; c < 128; c++){
        float4 w = *(const float4*)&lW1[c*56 + clb];
        float4 v = *(const float4*)&lrv1[c*64 + j4];
        e[0][0] += w.x*v.x; e[0][1] += w.x*v.y; e[0][2] += w.x*v.z; e[0][3] += w.x*v.w;
        e[1][0] += w.y*v.x; e[1][1] += w.y*v.y; e[1][2] += w.y*v.z; e[1][3] += w.y*v.w;
        e[2][0] += w.z*v.x; e[2][1] += w.z*v.y; e[2][2] += w.z*v.z; e[2][3] += w.z*v.w;
        e[3][0] += w.w*v.x; e[3][1] += w.w*v.y; e[3][2] += w.w*v.z; e[3][3] += w.w*v.w;
      }
    }
    __syncthreads();                 // E1 done reading lrv1 -> safe to overlay eU
    if(ig < 14){
      #pragma unroll
      for(int r = 0; r < 4; r++){
        float bias = bg1p[clb + r];
        float4 u;
        u.x = expf(e[r][0] + bias); u.y = expf(e[r][1] + bias);
        u.z = expf(e[r][2] + bias); u.w = expf(e[r][3] + bias);
        *(float4*)&lrv1[(clb + r)*64 + j4] = u;     // eU[cl][n]
      }
    }
    __syncthreads();
    // UCX accumulate: ua[d4..][c8..] += x[n][d] * eU[c][n]  (padded n: x==0)
    if(t < 231){
      int d4 = dg*4, cb8 = cg*8;
      #pragma unroll 2
      for(int n = 0; n < 64; n++){
        float4 xv = *(const float4*)&lxt[n*132 + d4];
        #pragma unroll
        for(int i = 0; i < 8; i++){
          float u = lrv1[(cb8 + i)*64 + n];
          ua[0][i] += xv.x*u; ua[1][i] += xv.y*u;
          ua[2][i] += xv.z*u; ua[3][i] += xv.w*u;
        }
      }
    }
    // E2 GEMM + global write
    if(ig < 14){
      #pragma unroll
      for(int r = 0; r < 4; r++){ e[r][0]=0.f; e[r][1]=0.f; e[r][2]=0.f; e[r][3]=0.f; }
      #pragma unroll 4
      for(int c = 0; c < 128; c++){
        float4 w = *(const float4*)&lW2[c*56 + clb];
        float4 v = *(const float4*)&lrv2[c*64 + j4];
        e[0][0] += w.x*v.x; e[0][1] += w.x*v.y; e[0][2] += w.x*v.z; e[0][3] += w.x*v.w;
        e[1][0] += w.y*v.x; e[1][1] += w.y*v.y; e[1][2] += w.y*v.z; e[1][3] += w.y*v.w;
        e[2][0] += w.z*v.x; e[2][1] += w.z*v.y; e[2][2] += w.z*v.z; e[2][3] += w.z*v.w;
        e[3][0] += w.w*v.x; e[3][1] += w.w*v.y; e[3][2] += w.w*v.z; e[3][3] += w.w*v.w;
      }
      if(j4 < lim){
        #pragma unroll
        for(int r = 0; r < 4; r++){
          int cl = clb + r;
          if(cl < 50){
            float bias = bg2p[cl];
            float4 o = make_float4(e[r][0]+bias, e[r][1]+bias, e[r][2]+bias, e[r][3]+bias);
            *(float4*)&ws[O_E2 + ((size_t)b*50 + cl)*4000 + nb + j4] = o;
          }
        }
      }
    }
  }
  // write partials [ch][b][132][56]
  if(t < 231){
    int d4 = dg*4, cb8 = cg*8;
    #pragma unroll
    for(int r = 0; r < 4; r++){
      size_t base = O_UCXP + ((size_t)(ch*64 + b)*132 + d4 + r)*56 + cb8;
      *(float4*)&ws[base]     = make_float4(ua[r][0], ua[r][1], ua[r][2], ua[r][3]);
      *(float4*)&ws[base + 4] = make_float4(ua[r][4], ua[r][5], ua[r][6], ua[r][7]);
    }
  }
}

// ---------------- K4: reduce partials, divide by Z -> cluster_x ----------------
__global__ __launch_bounds__(256) void k_cxred(float* __restrict__ ws){
  int b = blockIdx.x, t = threadIdx.x;
  __shared__ float zi[64];
  if(t < 50){
    float s = 0.f;
    for(int ch = 0; ch < 8; ch++)
      s += ws[O_UCXP + ((size_t)(ch*64 + b)*132 + 128)*56 + t];
    zi[t] = 1.f / s;
  }
  __syncthreads();
  for(int i = t; i < 6400; i += 256){
    int d = i / 50, c = i % 50;
    float s = 0.f;
    for(int ch = 0; ch < 8; ch++)
      s += ws[O_UCXP + ((size_t)(ch*64 + b)*132 + d)*56 + c];
    ws[O_CX + (size_t)b*6400 + d*50 + c] = s * zi[c];
  }
}

// ---------------- K5: qkv + qkv1 projections (512x128 @ 128x50 per b) ----------------
__global__ __launch_bounds__(256) void k_qkv(const float* __restrict__ qw,
                                             const float* __restrict__ qb,
                                             const float* __restrict__ q1w,
                                             const float* __restrict__ q1b,
                                             float* __restrict__ ws){
  int rt = blockIdx.x, b = blockIdx.y;        // 8 row-tiles of 64
  __shared__ float wl[64*130];                // [rl][k] pad 130
  __shared__ float cxl[128*52];               // [k][c]
  int t = threadIdx.x;
  for(int i = t; i < 2048; i += 256){
    int rl = i >> 5, kq = i & 31, row = rt*64 + rl;
    float4 w = (row < 128) ? *(const float4*)&qw[row*128 + kq*4]
                           : *(const float4*)&q1w[(row-128)*128 + kq*4];
    int k0 = kq*4;
    wl[rl*130 + k0+0] = w.x; wl[rl*130 + k0+1] = w.y;
    wl[rl*130 + k0+2] = w.z; wl[rl*130 + k0+3] = w.w;
  }
  for(int i = t; i < 6656; i += 256){
    int k = i / 52, c = i % 52;
    cxl[i] = (c < 50) ? ws[O_CX + (size_t)b*6400 + k*50 + c] : 0.f;
  }
  __syncthreads();
  int ig = t & 15, cg = t >> 4;               // rows ig*4, cols cg*4 (cg<13)
  float acc[4][4];
  #pragma unroll
  for(int r = 0; r < 4; r++){ acc[r][0]=0.f; acc[r][1]=0.f; acc[r][2]=0.f; acc[r][3]=0.f; }
  if(cg < 13){
    int rb = ig*4, cb = cg*4;
    #pragma unroll 4
    for(int k = 0; k < 128; k++){
      float4 cv = *(const float4*)&cxl[k*52 + cb];
      float w0 = wl[(rb+0)*130 + k], w1 = wl[(rb+1)*130 + k];
      float w2 = wl[(rb+2)*130 + k], w3 = wl[(rb+3)*130 + k];
      acc[0][0] += w0*cv.x; acc[0][1] += w0*cv.y; acc[0][2] += w0*cv.z; acc[0][3] += w0*cv.w;
      acc[1][0] += w1*cv.x; acc[1][1] += w1*cv.y; acc[1][2] += w1*cv.z; acc[1][3] += w1*cv.w;
      acc[2][0] += w2*cv.x; acc[2][1] += w2*cv.y; acc[2][2] += w2*cv.z; acc[2][3] += w2*cv.w;
      acc[3][0] += w3*cv.x; acc[3][1] += w3*cv.y; acc[3][2] += w3*cv.z; acc[3][3] += w3*cv.w;
    }
    #pragma unroll
    for(int r = 0; r < 4; r++){
      int row = rt*64 + ig*4 + r;
      size_t base; float bias;
      if(row < 128){
        int h = row >> 5;
        bias = qb[row];
        base = O_XT + (size_t)(b*4 + h)*1600 + (row & 31);
      }else{
        int r2 = row - 128, h = r2/96, j = r2%96, kind = j >> 5, dd = j & 31;
        bias = q1b[r2];
        base = (kind==0 ? O_QT : kind==1 ? O_KT : O_VT) + (size_t)(b*4 + h)*1600 + dd;
      }
      #pragma unroll
      for(int s = 0; s < 4; s++){
        int c = cg*4 + s;
        if(c < 50) ws[base + (size_t)c*32] = acc[r][s] + bias;
      }
    }
  }
}

// ---------------- K6: knn (top-9, jax tie order) + edge + conv1 ----------------
__global__ __launch_bounds__(256) void k_knn(const float* __restrict__ g1w,
                                             const float* __restrict__ g1bias,
                                             float* __restrict__ ws){
  int h = blockIdx.x, b = blockIdx.y;
  __shared__ float xtl[50][33];
  __shared__ float pdl[50][52];
  __shared__ float sql[50];
  __shared__ int   idxl[50][9];
  __shared__ float w1l[6144];                 // [(i*3+t)*32+o]
  int t = threadIdx.x;
  const float* xtg = ws + O_XT + (size_t)(b*4 + h)*1600;
  for(int i = t; i < 1600; i += 256) xtl[i >> 5][i & 31] = xtg[i];
  for(int i = t; i < 6144; i += 256){
    int o = i / 192, r = i % 192, ii = r / 3, tt = r % 3;
    w1l[(ii*3 + tt)*32 + o] = g1w[(size_t)h*6144 + i];
  }
  __syncthreads();
  if(t < 50){
    float s = 0.f;
    for(int d = 0; d < 32; d++){ float v = xtl[t][d]; s += v*v; }
    sql[t] = s;
  }
  __syncthreads();
  for(int i = t; i < 2500; i += 256){
    int n = i / 50, m = i % 50;
    float s = 0.f;
    for(int d = 0; d < 32; d++) s += xtl[n][d]*xtl[m][d];
    pdl[n][m] = 2.f*s - sql[n] - sql[m];
  }
  __syncthreads();
  if(t < 50){
    float pv = INFINITY; int pi = -1;
    for(int k = 0; k < 9; k++){
      float bv = -INFINITY; int bi = 1000;
      for(int m = 0; m < 50; m++){
        float v = pdl[t][m];
        bool elig = (v < pv) || (v == pv && m > pi);
        if(elig && (v > bv || (v == bv && m < bi))){ bv = v; bi = m; }
      }
      idxl[t][k] = bi; pv = bv; pi = bi;
    }
  }
  __syncthreads();
  if(t < 150){
    int n = t / 3, jw = t % 3;
    float acc[32];
    #pragma unroll
    for(int o = 0; o < 32; o++) acc[o] = 0.f;
    for(int t3 = 0; t3 < 3; t3++){
      int kx = idxl[n][jw*3 + t3];
      for(int ii = 0; ii < 32; ii++){
        float c0 = xtl[n][ii];
        float c1 = c0 - xtl[kx][ii];
        const float* wr0 = w1l + (ii*3 + t3)*32;
        const float* wr1 = w1l + ((ii+32)*3 + t3)*32;
        #pragma unroll
        for(int o = 0; o < 32; o++) acc[o] += c0*wr0[o] + c1*wr1[o];
      }
    }
    float* out = ws + O_H1 + ((size_t)(b*4 + h)*150 + n*3 + jw)*32;
    #pragma unroll
    for(int o = 0; o < 32; o++) out[o] = acc[o] + g1bias[h*32 + o];
  }
}

// ---------------- K7: BN1 stats ----------------
__global__ void k_bn1p(float* __restrict__ ws){
  int b = blockIdx.x, t = threadIdx.x;
  int p = t & 127, half = t >> 7;
  int h = p >> 5, o = p & 31;
  const float* src = ws + O_H1 + (size_t)b*19200;
  float s = 0.f, sq = 0.f;
  for(int nj = half*75; nj < half*75 + 75; nj++){
    float v = src[(h*150 + nj)*32 + o];
    s += v; sq += v*v;
  }
  __shared__ float ls[256], lq[256];
  ls[t] = s; lq[t] = sq; __syncthreads();
  if(t < 128){
    ws[O_P1 + b*256 + p]       = ls[t] + ls[t+128];
    ws[O_P1 + b*256 + 128 + p] = lq[t] + lq[t+128];
  }
}

__global__ void k_bn1f(const float* g, const float* be, float* __restrict__ ws){
  int t = threadIdx.x;
  if(t < 128){
    float s = 0.f, sq = 0.f;
    for(int b = 0; b < 64; b++){ s += ws[O_P1 + b*256 + t]; sq += ws[O_P1 + b*256 + 128 + t]; }
    float mean = s * (1.f/9600.f), var = sq * (1.f/9600.f) - mean*mean;
    float sc = g[t] * rsqrtf(var + 1e-5f);
    ws[O_BN1S+t] = sc; ws[O_BN1T+t] = be[t] - sc*mean;
  }
}

// ---------------- K8: BN1+relu then conv2 (1x3) + BN2 partials ----------------
__global__ __launch_bounds__(256) void k_conv2(const float* __restrict__ g2w,
                                               const float* __restrict__ g2bias,
                                               float* __restrict__ ws){
  int h = blockIdx.x, b = blockIdx.y;
  __shared__ float hl[150][33];
  __shared__ float w2l[3072];
  __shared__ float rs[8][32], rq[8][32];
  int t = threadIdx.x;
  const float* h1p = ws + O_H1 + (size_t)(b*4 + h)*4800;
  for(int i = t; i < 4800; i += 256){
    int nj = i >> 5, ii = i & 31;
    hl[nj][ii] = fmaxf(ws[O_BN1S + h*32 + ii]*h1p[i] + ws[O_BN1T + h*32 + ii], 0.f);
  }
  for(int i = t; i < 3072; i += 256){
    int o = i / 96, r = i % 96, ii = r / 3, tt = r % 3;
    w2l[(ii*3 + tt)*32 + o] = g2w[(size_t)h*3072 + i];
  }
  __syncthreads();
  int o = t & 31, ng = t >> 5;
  float bias = g2bias[h*32 + o];
  float s = 0.f, sq = 0.f;
  for(int n = ng; n < 50; n += 8){
    float acc = 0.f;
    for(int t3 = 0; t3 < 3; t3++){
      const float* hr = hl[n*3 + t3];
      #pragma unroll
      for(int ii = 0; ii < 32; ii++) acc += hr[ii] * w2l[(ii*3 + t3)*32 + o];
    }
    acc += bias;
    ws[O_H2 + ((size_t)(b*4 + h)*50 + n)*32 + o] = acc;
    s += acc; sq += acc*acc;
  }
  rs[ng][o] = s; rq[ng][o] = sq; __syncthreads();
  if(t < 32){
    float S = 0.f, Q = 0.f;
    for(int g2 = 0; g2 < 8; g2++){ S += rs[g2][t]; Q += rq[g2][t]; }
    ws[O_P2 + (b*4 + h)*64 + t]      = S;
    ws[O_P2 + (b*4 + h)*64 + 32 + t] = Q;
  }
}

__global__ void k_bn2f(const float* g, const float* be, float* __restrict__ ws){
  int t = threadIdx.x;
  if(t < 128){
    int h = t >> 5, o = t & 31;
    float s = 0.f, sq = 0.f;
    for(int b = 0; b < 64; b++){
      s  += ws[O_P2 + (size_t)(b*4 + h)*64 + o];
      sq += ws[O_P2 + (size_t)(b*4 + h)*64 + 32 + o];
    }
    float mean = s * (1.f/3200.f), var = sq * (1.f/3200.f) - mean*mean;
    float sc = g[t] * rsqrtf(var + 1e-5f);
    ws[O_BN2S+t] = sc; ws[O_BN2T+t] = be[t] - sc*mean;
  }
}

// ---------------- K9: tiny attention + assemble cat [b][256][50] ----------------
__global__ __launch_bounds__(256) void k_attn(float* __restrict__ ws){
  int h = blockIdx.x, b = blockIdx.y;
  __shared__ float qtl[50][33], ktl[50][33], vtl[50][33], al[50][52];
  int t = threadIdx.x;
  size_t base = (size_t)(b*4 + h)*1600;
  for(int i = t; i < 1600; i += 256){
    int n = i >> 5, d = i & 31;
    qtl[n][d] = ws[O_QT + base + i];
    ktl[n][d] = ws[O_KT + base + i];
    vtl[n][d] = ws[O_VT + base + i];
  }
  __syncthreads();
  for(int i = t; i < 2500; i += 256){
    int n = i / 50, m = i % 50;
    float s = 0.f;
    for(int d = 0; d < 32; d++) s += qtl[n][d]*ktl[m][d];
    al[n][m] = s * 0.17677669529663687f;
  }
  __syncthreads();
  if(t < 50){
    float m = -INFINITY;
    for(int j = 0; j < 50; j++) m = fmaxf(m, al[t][j]);
    float s = 0.f;
    for(int j = 0; j < 50; j++){ float e = expf(al[t][j] - m); al[t][j] = e; s += e; }
    float inv = 1.f/s;
    for(int j = 0; j < 50; j++) al[t][j] *= inv;
  }
  __syncthreads();
  for(int i = t; i < 1600; i += 256){
    int n = i >> 5, d = i & 31;
    float gacc = 0.f;
    for(int m = 0; m < 50; m++) gacc += al[n][m]*vtl[m][d];
    ws[O_CAT + ((size_t)b*256 + h*64 + 32 + d)*50 + n] = gacc;
    float l = fmaxf(ws[O_BN2S + h*32 + d]*ws[O_H2 + ((size_t)(b*4 + h)*50 + n)*32 + d] + ws[O_BN2T + h*32 + d], 0.f);
    ws[O_CAT + ((size_t)b*256 + h*64 + d)*50 + n] = l;
  }
}

// ---------------- K10: pres2[b][c][o] = (M @ cat)[o][c] + vproj[o] ----------------
__global__ __launch_bounds__(256) void k_res(float* __restrict__ ws){
  int b = blockIdx.x;
  __shared__ float mtl[64*132];    // [k][o] pad 132
  __shared__ float catl[64*52];    // [k][c]
  __shared__ float vp[128];
  int t = threadIdx.x;
  if(t < 128) vp[t] = ws[O_VPROJ + t];
  int og = t >> 4, cg = t & 15;    // ob = og*8 (128 o), cb = cg*4 (cg<13)
  int ob = og*8, cb = cg*4;
  float acc[8][4];
  #pragma unroll
  for(int r = 0; r < 8; r++){ acc[r][0]=0.f; acc[r][1]=0.f; acc[r][2]=0.f; acc[r][3]=0.f; }
  for(int kc = 0; kc < 4; kc++){
    int k0 = kc*64;
    __syncthreads();
    for(int i = t; i < 2048; i += 256){
      int k = i >> 5, oq = i & 31;
      float4 m = *(const float4*)&ws[O_MT + (size_t)(k0 + k)*128 + oq*4];
      *(float4*)&mtl[k*132 + oq*4] = m;
    }
    for(int i = t; i < 3328; i += 256){
      int k = i / 52, c = i % 52;
      catl[i] = (c < 50) ? ws[O_CAT + (size_t)b*12800 + (k0 + k)*50 + c] : 0.f;
    }
    __syncthreads();
    if(cg < 13){
      #pragma unroll 2
      for(int k = 0; k < 64; k++){
        float4 m0 = *(const float4*)&mtl[k*132 + ob];
        float4 m1 = *(const float4*)&mtl[k*132 + ob + 4];
        float4 cv = *(const float4*)&catl[k*52 + cb];
        acc[0][0] += m0.x*cv.x; acc[0][1] += m0.x*cv.y; acc[0][2] += m0.x*cv.z; acc[0][3] += m0.x*cv.w;
        acc[1][0] += m0.y*cv.x; acc[1][1] += m0.y*cv.y; acc[1][2] += m0.y*cv.z; acc[1][3] += m0.y*cv.w;
        acc[2][0] += m0.z*cv.x; acc[2][1] += m0.z*cv.y; acc[2][2] += m0.z*cv.z; acc[2][3] += m0.z*cv.w;
        acc[3][0] += m0.w*cv.x; acc[3][1] += m0.w*cv.y; acc[3][2] += m0.w*cv.z; acc[3][3] += m0.w*cv.w;
        acc[4][0] += m1.x*cv.x; acc[4][1] += m1.x*cv.y; acc[4][2] += m1.x*cv.z; acc[4][3] += m1.x*cv.w;
        acc[5][0] += m1.y*cv.x; acc[5][1] += m1.y*cv.y; acc[5][2] += m1.y*cv.z; acc[5][3] += m1.y*cv.w;
        acc[6][0] += m1.z*cv.x; acc[6][1] += m1.z*cv.y; acc[6][2] += m1.z*cv.z; acc[6][3] += m1.z*cv.w;
        acc[7][0] += m1.w*cv.x; acc[7][1] += m1.w*cv.y; acc[7][2] += m1.w*cv.z; acc[7][3] += m1.w*cv.w;
      }
    }
  }
  if(cg < 13){
    #pragma unroll
    for(int s = 0; s < 4; s++){
      int c = cb + s;
      if(c < 50){
        float4 o0 = make_float4(acc[0][s]+vp[ob+0], acc[1][s]+vp[ob+1], acc[2][s]+vp[ob+2], acc[3][s]+vp[ob+3]);
        float4 o1 = make_float4(acc[4][s]+vp[ob+4], acc[5][s]+vp[ob+5], acc[6][s]+vp[ob+6], acc[7][s]+vp[ob+7]);
        *(float4*)&ws[O_PRES2 + (size_t)b*6400 + c*128 + ob]     = o0;
        *(float4*)&ws[O_PRES2 + (size_t)b*6400 + c*128 + ob + 4] = o1;
      }
    }
  }
}

// ---------------- K11: out = pres2 @ softmax_cl(embed2) + proj_b ----------------
__global__ __launch_bounds__(256) void k_out(const float* __restrict__ projb,
                                             float* __restrict__ ws,
                                             float* __restrict__ out){
  int nt = blockIdx.x, b = blockIdx.y;
  int n0 = nt*64;
  __shared__ float sl[50*64];      // [c][j]
  __shared__ float p2l[50*132];    // [c][o] pad 132
  __shared__ float pb[128];
  int t = threadIdx.x;
  for(int i = t; i < 3200; i += 256){
    int c = i >> 6, j = i & 63, n = n0 + j;
    sl[i] = (n < 4000) ? ws[O_E2 + ((size_t)b*50 + c)*4000 + n] : 0.f;
  }
  for(int i = t; i < 6400; i += 256){
    int c = i >> 7, o = i & 127;
    p2l[c*132 + o] = ws[O_PRES2 + (size_t)b*6400 + c*128 + o];
  }
  if(t < 128) pb[t] = projb[t];
  __syncthreads();
  if(t < 64){
    int j = t;
    float m = -INFINITY;
    for(int c = 0; c < 50; c++) m = fmaxf(m, sl[c*64 + j]);
    float s = 0.f;
    for(int c = 0; c < 50; c++){ float e = expf(sl[c*64 + j] - m); sl[c*64 + j] = e; s += e; }
    float inv = 1.f/s;
    for(int c = 0; c < 50; c++) sl[c*64 + j] *= inv;
  }
  __syncthreads();
  int og = t >> 4, jg = t & 15;
  int ob = og*8, j4 = jg*4;
  float acc[8][4];
  #pragma unroll
  for(int r = 0; r < 8; r++){ acc[r][0]=0.f; acc[r][1]=0.f; acc[r][2]=0.f; acc[r][3]=0.f; }
  #pragma unroll 2
  for(int c = 0; c < 50; c++){
    float4 sv = *(const float4*)&sl[c*64 + j4];
    float4 p0 = *(const float4*)&p2l[c*132 + ob];
    float4 p1 = *(const float4*)&p2l[c*132 + ob + 4];
    acc[0][0] += p0.x*sv.x; acc[0][1] += p0.x*sv.y; acc[0][2] += p0.x*sv.z; acc[0][3] += p0.x*sv.w;
    acc[1][0] += p0.y*sv.x; acc[1][1] += p0.y*sv.y; acc[1][2] += p0.y*sv.z; acc[1][3] += p0.y*sv.w;
    acc[2][0] += p0.z*sv.x; acc[2][1] += p0.z*sv.y; acc[2][2] += p0.z*sv.z; acc[2][3] += p0.z*sv.w;
    acc[3][0] += p0.w*sv.x; acc[3][1] += p0.w*sv.y; acc[3][2] += p0.w*sv.z; acc[3][3] += p0.w*sv.w;
    acc[4][0] += p1.x*sv.x; acc[4][1] += p1.x*sv.y; acc[4][2] += p1.x*sv.z; acc[4][3] += p1.x*sv.w;
    acc[5][0] += p1.y*sv.x; acc[5][1] += p1.y*sv.y; acc[5][2] += p1.y*sv.z; acc[5][3] += p1.y*sv.w;
    acc[6][0] += p1.z*sv.x; acc[6][1] += p1.z*sv.y; acc[6][2] += p1.z*sv.z; acc[6][3] += p1.z*sv.w;
    acc[7][0] += p1.w*sv.x; acc[7][1] += p1.w*sv.y; acc[7][2] += p1.w*sv.z; acc[7][3] += p1.w*sv.w;
  }
  int n = n0 + j4;
  if(n < 4000){
    #pragma unroll
    for(int r = 0; r < 8; r++){
      float bv = pb[ob + r];
      float4 o = make_float4(acc[r][0]+bv, acc[r][1]+bv, acc[r][2]+bv, acc[r][3]+bv);
      *(float4*)&out[(size_t)(b*128 + ob + r)*4000 + n] = o;
    }
  }
}

extern "C" void kernel_launch(void* const* d_in, const int* in_sizes, int n_in,
                              void* d_out, int out_size, void* d_ws, size_t ws_size,
                              hipStream_t stream){
  (void)in_sizes; (void)n_in; (void)out_size; (void)ws_size;
  const float* x      = (const float*)d_in[0];
  const float* wg1    = (const float*)d_in[1];
  const float* bg1    = (const float*)d_in[2];
  const float* g1g    = (const float*)d_in[3];
  const float* g1b    = (const float*)d_in[4];
  const float* wg2    = (const float*)d_in[5];
  const float* bg2    = (const float*)d_in[6];
  const float* g2g    = (const float*)d_in[7];
  const float* g2b    = (const float*)d_in[8];
  const float* qkvw   = (const float*)d_in[9];
  const float* qkvb   = (const float*)d_in[10];
  const float* qkv1w  = (const float*)d_in[11];
  const float* qkv1b  = (const float*)d_in[12];
  const float* gc1w   = (const float*)d_in[13];
  const float* gc1bias= (const float*)d_in[14];
  const float* gc1g   = (const float*)d_in[15];
  const float* gc1be  = (const float*)d_in[16];
  const float* gc2w   = (const float*)d_in[17];
  const float* gc2bias= (const float*)d_in[18];
  const float* gc2g   = (const float*)d_in[19];
  const float* gc2be  = (const float*)d_in[20];
  const float* presw  = (const float*)d_in[21];
  const float* presb  = (const float*)d_in[22];
  const float* projw  = (const float*)d_in[23];
  const float* projb  = (const float*)d_in[24];
  float* ws = (float*)d_ws;
  float* out = (float*)d_out;

  k_rowstats<<<8192, 256, 0, stream>>>(x, ws);
  k_prep<<<1, 256, 0, stream>>>(g1g, g1b, g2g, g2b, presb, projw, ws);
  k_mprep<<<128, 256, 0, stream>>>(presw, ws);
  k_fused<<<dim3(8, 64), 256, 0, stream>>>(x, wg1, bg1, wg2, bg2, ws);
  k_cxred<<<64, 256, 0, stream>>>(ws);
  k_qkv<<<dim3(8, 64), 256, 0, stream>>>(qkvw, qkvb, qkv1w, qkv1b, ws);
  k_knn<<<dim3(4, 64), 256, 0, stream>>>(gc1w, gc1bias, ws);
  k_bn1p<<<64, 256, 0, stream>>>(ws);
  k_bn1f<<<1, 128, 0, stream>>>(gc1g, gc1be, ws);
  k_conv2<<<dim3(4, 64), 256, 0, stream>>>(gc2w, gc2bias, ws);
  k_bn2f<<<1, 128, 0, stream>>>(gc2g, gc2be, ws);
  k_attn<<<dim3(4, 64), 256, 0, stream>>>(ws);
  k_res<<<64, 256, 0, stream>>>(ws);
  k_out<<<dim3(63, 64), 256, 0, stream>>>(projb, ws, out);
}

// Round 2
// 796.848 us; speedup vs baseline: 1.0863x; 1.0863x over previous
//
#include <hip/hip_runtime.h>
#include <cstddef>

// EfficientAttention pipeline, MI355X. fp32 throughout.
// B=64, DIM=128, N=4000, H=4, DH=32, CL=50, K=9.
// R5: k_fused split into k_e1ucx (77.8 KB LDS) + k_e2 (59 KB LDS) so each gets
// 2 blocks/CU (was 155 KB -> 1 block/CU, Occupancy 11.6%, VALUBusy 41%).
// UCX inner loop re-vectorized: eU read as b128 over n (was 8x b32 per n).

// ---- workspace offsets (in floats) ----
constexpr size_t O_MU    = 0;                   // 8192
constexpr size_t O_RINV  = 8192;                // 8192
constexpr size_t O_RATIO = 16384;               // 8192
constexpr size_t O_A1    = 24576;               // 128
constexpr size_t O_B1    = 24704;
constexpr size_t O_A2    = 24832;
constexpr size_t O_B2    = 24960;
constexpr size_t O_PROJWT= 25088;               // 128x128 proj_w^T [d][o]
constexpr size_t O_VPROJ = 41472;               // 128  projw@pres_b
constexpr size_t O_MT    = 41600;               // 256x128  M^T [k][o], M=projw@presw
constexpr size_t O_E2    = 74368;               // 64*50*4000
constexpr size_t O_UCXP  = 12874368;            // 8*64*132*56 fused GEMM partials
constexpr size_t O_CX    = 16659072;            // 64*128*50 [b][d][c]
constexpr size_t O_XT    = 17068672;            // 64*4*50*32 [b][h][c][d]
constexpr size_t O_QT    = 17478272;
constexpr size_t O_KT    = 17887872;
constexpr size_t O_VT    = 18297472;
constexpr size_t O_H1    = 18707072;            // 64*4*150*32
constexpr size_t O_P1    = 19935872;            // 64*256
constexpr size_t O_BN1S  = 19952256;            // 128
constexpr size_t O_BN1T  = 19952384;
constexpr size_t O_H2    = 19952512;            // 64*4*50*32
constexpr size_t O_P2    = 20362112;            // 256*64
constexpr size_t O_BN2S  = 20378496;
constexpr size_t O_BN2T  = 20378624;
constexpr size_t O_CAT   = 20378752;            // 64*256*50 [b][ch][n]
constexpr size_t O_PRES2 = 21197952;            // 64*50*128 [b][c][o]

// ---------------- K1: per-(b,c) instance-norm stats over n=4000 ----------------
__global__ __launch_bounds__(256) void k_rowstats(const float* __restrict__ x,
                                                  float* __restrict__ ws){
  int row = blockIdx.x;                       // b*128+c
  const float4* xr = (const float4*)(x + (size_t)row * 4000);
  float s = 0.f, sq = 0.f;
  for(int i = threadIdx.x; i < 1000; i += 256){
    float4 v = xr[i];
    s  += v.x + v.y + v.z + v.w;
    sq += v.x*v.x + v.y*v.y + v.z*v.z + v.w*v.w;
  }
  __shared__ float ls[256], lq[256];
  ls[threadIdx.x] = s; lq[threadIdx.x] = sq; __syncthreads();
  for(int st = 128; st > 0; st >>= 1){
    if(threadIdx.x < st){ ls[threadIdx.x] += ls[threadIdx.x+st]; lq[threadIdx.x] += lq[threadIdx.x+st]; }
    __syncthreads();
  }
  if(threadIdx.x == 0){
    float mean = ls[0] * (1.f/4000.f);
    float var  = lq[0] * (1.f/4000.f) - mean*mean;
    ws[O_MU   + row] = mean;
    ws[O_RINV + row] = rsqrtf(var + 1e-3f);
    ws[O_RATIO+ row] = var / (var + 1e-3f);
  }
}

// ---------------- K2: BN stats (mu2==0 exactly) + small weight prep ----------------
__global__ void k_prep(const float* g1g, const float* g1b,
                       const float* g2g, const float* g2b,
                       const float* presb, const float* projw,
                       float* __restrict__ ws){
  int t = threadIdx.x;
  if(t < 128){
    float s = 0.f;
    for(int b = 0; b < 64; b++) s += ws[O_RATIO + b*128 + t];
    float var2 = s * (1.f/64.f);
    float inv2 = rsqrtf(var2 + 1e-5f);
    ws[O_A1+t] = g1g[t] * inv2;  ws[O_B1+t] = g1b[t];
    ws[O_A2+t] = g2g[t] * inv2;  ws[O_B2+t] = g2b[t];
  }
  for(int i = t; i < 16384; i += 256){ int o = i & 127, k = i >> 7; ws[O_PROJWT+i] = projw[o*128 + k]; }
  __syncthreads();
  if(t < 128){
    float v = 0.f;
    for(int d = 0; d < 128; d++) v += ws[O_PROJWT + d*128 + t] * presb[d];
    ws[O_VPROJ + t] = v;
  }
}

// ---------------- K2b: M^T[k][o] = sum_d projw^T[d][o] * presw[d][k] ----------------
__global__ __launch_bounds__(256) void k_mprep(const float* __restrict__ presw,
                                               float* __restrict__ ws){
  int kk2 = blockIdx.x * 2;                   // 128 blocks
  __shared__ float pwc[2][128];
  int t = threadIdx.x;
  { int which = t >> 7, d = t & 127; pwc[which][d] = presw[d*256 + kk2 + which]; }
  __syncthreads();
  int which = t >> 7, o = t & 127;
  float acc = 0.f;
  for(int d = 0; d < 128; d++) acc += ws[O_PROJWT + d*128 + o] * pwc[which][d];
  ws[O_MT + (size_t)(kk2 + which)*128 + o] = acc;
}

// ---------------- K3a: embed1 + exp + unnormalized cluster GEMM partials + Z ----------------
// grid (8 ch, 64 b), 256 thr, n-tile 48, 11 subtiles (last lim=20). LDS ~77.8 KB -> 2 blocks/CU.
__global__ __launch_bounds__(256) void k_e1ucx(const float* __restrict__ x,
    const float* __restrict__ wg1, const float* __restrict__ bg1,
    float* __restrict__ ws){
  int ch = blockIdx.x, b = blockIdx.y;
  __shared__ float lW1[128*52];     // [c][cl], cl padded 52 (rows 50,51 zero)
  __shared__ float lrv1[128*48];    // relu1 [c][n]; after E1: eU overlay [52][48]
  __shared__ float lxt [48*132];    // x^T [n][d], pad 132
  __shared__ float ca1[128], cb1[128];
  __shared__ float bg1p[56];
  int t = threadIdx.x;
  if(t < 128){
    float mu = ws[O_MU + b*128 + t], ri = ws[O_RINV + b*128 + t];
    float a1 = ws[O_A1+t]*ri;
    ca1[t] = a1; cb1[t] = ws[O_B1+t] - a1*mu;
  }
  if(t < 56) bg1p[t] = (t < 50) ? bg1[t] : 0.f;
  for(int i = t; i < 1664; i += 256){         // 52 cl rows x 32 float4 over c
    int cl = i >> 5, cq = i & 31;
    float4 w = (cl < 50) ? *(const float4*)&wg1[cl*128 + cq*4] : make_float4(0.f,0.f,0.f,0.f);
    int c0 = cq*4;
    lW1[(c0+0)*52+cl] = w.x; lW1[(c0+1)*52+cl] = w.y;
    lW1[(c0+2)*52+cl] = w.z; lW1[(c0+3)*52+cl] = w.w;
  }
  // UCX map: 224 active threads, tile 4d x 8c
  int dg = t & 31, cg = t >> 5;               // d4 = dg*4, c8 = cg*8 (cg<7)
  float ua[4][8];
  #pragma unroll
  for(int r = 0; r < 4; r++)
    #pragma unroll
    for(int i = 0; i < 8; i++) ua[r][i] = 0.f;
  float zacc = 0.f;
  // E1 map: tile 4cl x 4n, active ig<13 && jg<12
  int ig = t >> 4, jg = t & 15;
  int clb = ig*4, j4 = jg*4;

  for(int st = 0; st < 11; st++){
    int nb = ch*500 + st*48;
    int lim = (st == 10) ? 20 : 48;
    __syncthreads();
    // stage: x^T tile + relu1
    for(int i = t; i < 1536; i += 256){
      int c = i / 12, jj = (i % 12)*4;
      float4 xv = make_float4(0.f,0.f,0.f,0.f);
      if(jj < lim) xv = *(const float4*)&x[(size_t)(b*128 + c)*4000 + nb + jj];
      lxt[(jj+0)*132 + c] = xv.x; lxt[(jj+1)*132 + c] = xv.y;
      lxt[(jj+2)*132 + c] = xv.z; lxt[(jj+3)*132 + c] = xv.w;
      float a1 = ca1[c], b1v = cb1[c];
      float4 r1;
      r1.x = fmaxf(a1*xv.x + b1v, 0.f); r1.y = fmaxf(a1*xv.y + b1v, 0.f);
      r1.z = fmaxf(a1*xv.z + b1v, 0.f); r1.w = fmaxf(a1*xv.w + b1v, 0.f);
      *(float4*)&lrv1[c*48 + jj] = r1;
    }
    __syncthreads();
    // E1 GEMM: 52 rows x 48 cols
    float e[4][4];
    if(ig < 13 && jg < 12){
      #pragma unroll
      for(int r = 0; r < 4; r++){ e[r][0]=0.f; e[r][1]=0.f; e[r][2]=0.f; e[r][3]=0.f; }
      #pragma unroll 4
      for(int c = 0; c < 128; c++){
        float4 w = *(const float4*)&lW1[c*52 + clb];
        float4 v = *(const float4*)&lrv1[c*48 + j4];
        e[0][0] += w.x*v.x; e[0][1] += w.x*v.y; e[0][2] += w.x*v.z; e[0][3] += w.x*v.w;
        e[1][0] += w.y*v.x; e[1][1] += w.y*v.y; e[1][2] += w.y*v.z; e[1][3] += w.y*v.w;
        e[2][0] += w.z*v.x; e[2][1] += w.z*v.y; e[2][2] += w.z*v.z; e[2][3] += w.z*v.w;
        e[3][0] += w.w*v.x; e[3][1] += w.w*v.y; e[3][2] += w.w*v.z; e[3][3] += w.w*v.w;
      }
    }
    __syncthreads();                 // E1 reads of lrv1 done -> overlay eU
    if(ig < 13 && jg < 12){
      bool live = (j4 < lim);
      #pragma unroll
      for(int r = 0; r < 4; r++){
        float bias = bg1p[clb + r];
        float4 u = make_float4(0.f,0.f,0.f,0.f);
        if(live){
          u.x = expf(e[r][0] + bias); u.y = expf(e[r][1] + bias);
          u.z = expf(e[r][2] + bias); u.w = expf(e[r][3] + bias);
        }
        *(float4*)&lrv1[(clb + r)*48 + j4] = u;     // eU[cl][n], masked to 0 past lim
      }
    }
    __syncthreads();
    // UCX accumulate: ua[d][c] += x[d][n]*eU[c][n], b128 over n for eU
    if(t < 224){
      int d4 = dg*4, c8 = cg*8;
      for(int n4 = 0; n4 < 12; n4++){
        int n0 = n4*4;
        float4 uv[8];
        #pragma unroll
        for(int i = 0; i < 8; i++) uv[i] = *(const float4*)&lrv1[(c8 + i)*48 + n0];
        {
          float4 xq = *(const float4*)&lxt[(n0+0)*132 + d4];
          #pragma unroll
          for(int i = 0; i < 8; i++){
            float u = uv[i].x;
            ua[0][i] += xq.x*u; ua[1][i] += xq.y*u; ua[2][i] += xq.z*u; ua[3][i] += xq.w*u;
          }
        }
        {
          float4 xq = *(const float4*)&lxt[(n0+1)*132 + d4];
          #pragma unroll
          for(int i = 0; i < 8; i++){
            float u = uv[i].y;
            ua[0][i] += xq.x*u; ua[1][i] += xq.y*u; ua[2][i] += xq.z*u; ua[3][i] += xq.w*u;
          }
        }
        {
          float4 xq = *(const float4*)&lxt[(n0+2)*132 + d4];
          #pragma unroll
          for(int i = 0; i < 8; i++){
            float u = uv[i].z;
            ua[0][i] += xq.x*u; ua[1][i] += xq.y*u; ua[2][i] += xq.z*u; ua[3][i] += xq.w*u;
          }
        }
        {
          float4 xq = *(const float4*)&lxt[(n0+3)*132 + d4];
          #pragma unroll
          for(int i = 0; i < 8; i++){
            float u = uv[i].w;
            ua[0][i] += xq.x*u; ua[1][i] += xq.y*u; ua[2][i] += xq.z*u; ua[3][i] += xq.w*u;
          }
        }
      }
    }
    // Z: row-sum of masked eU
    if(t < 52){
      float s = 0.f;
      #pragma unroll
      for(int k = 0; k < 12; k++){
        float4 u = *(const float4*)&lrv1[t*48 + k*4];
        s += u.x + u.y + u.z + u.w;
      }
      zacc += s;
    }
  }
  // write partials [ch][b][132][56]: rows 0..127 = UCX, row 128 = Z
  if(t < 224){
    int d4 = dg*4, c8 = cg*8;
    #pragma unroll
    for(int r = 0; r < 4; r++){
      size_t base = O_UCXP + ((size_t)(ch*64 + b)*132 + d4 + r)*56 + c8;
      *(float4*)&ws[base]     = make_float4(ua[r][0], ua[r][1], ua[r][2], ua[r][3]);
      *(float4*)&ws[base + 4] = make_float4(ua[r][4], ua[r][5], ua[r][6], ua[r][7]);
    }
  }
  if(t < 52) ws[O_UCXP + ((size_t)(ch*64 + b)*132 + 128)*56 + t] = zacc;
}

// ---------------- K3b: embed2 (pre-softmax logits) -> O_E2 ----------------
// grid (8 ch, 64 b), 256 thr, n-tile 64, 8 subtiles (last lim=52). LDS ~59 KB -> 2 blocks/CU.
__global__ __launch_bounds__(256) void k_e2(const float* __restrict__ x,
    const float* __restrict__ wg2, const float* __restrict__ bg2,
    float* __restrict__ ws){
  int ch = blockIdx.x, b = blockIdx.y;
  __shared__ float lW2[128*52];     // [c][cl], rows 50,51 zero
  __shared__ float lrv2[128*64];    // relu2 [c][n]
  __shared__ float ca2[128], cb2[128];
  __shared__ float bg2p[56];
  int t = threadIdx.x;
  if(t < 128){
    float mu = ws[O_MU + b*128 + t], ri = ws[O_RINV + b*128 + t];
    float a2 = ws[O_A2+t]*ri;
    ca2[t] = a2; cb2[t] = ws[O_B2+t] - a2*mu;
  }
  if(t < 56) bg2p[t] = (t < 50) ? bg2[t] : 0.f;
  for(int i = t; i < 1664; i += 256){
    int cl = i >> 5, cq = i & 31;
    float4 w = (cl < 50) ? *(const float4*)&wg2[cl*128 + cq*4] : make_float4(0.f,0.f,0.f,0.f);
    int c0 = cq*4;
    lW2[(c0+0)*52+cl] = w.x; lW2[(c0+1)*52+cl] = w.y;
    lW2[(c0+2)*52+cl] = w.z; lW2[(c0+3)*52+cl] = w.w;
  }
  int ig = t >> 4, jg = t & 15;
  int clb = ig*4, j4 = jg*4;
  for(int st = 0; st < 8; st++){
    int nb = ch*500 + st*64;
    int lim = (st == 7) ? 52 : 64;
    __syncthreads();
    for(int i = t; i < 2048; i += 256){
      int c = i >> 4, jj = (i & 15)*4;
      float4 xv = make_float4(0.f,0.f,0.f,0.f);
      if(jj < lim) xv = *(const float4*)&x[(size_t)(b*128 + c)*4000 + nb + jj];
      float a2 = ca2[c], b2v = cb2[c];
      float4 r2;
      r2.x = fmaxf(a2*xv.x + b2v, 0.f); r2.y = fmaxf(a2*xv.y + b2v, 0.f);
      r2.z = fmaxf(a2*xv.z + b2v, 0.f); r2.w = fmaxf(a2*xv.w + b2v, 0.f);
      *(float4*)&lrv2[c*64 + jj] = r2;
    }
    __syncthreads();
    if(ig < 13){
      float e[4][4];
      #pragma unroll
      for(int r = 0; r < 4; r++){ e[r][0]=0.f; e[r][1]=0.f; e[r][2]=0.f; e[r][3]=0.f; }
      #pragma unroll 4
      for(int c = 0; c < 128; c++){
        float4 w = *(const float4*)&lW2[c*52 + clb];
        float4 v = *(const float4*)&lrv2[c*64 + j4];
        e[0][0] += w.x*v.x; e[0][1] += w.x*v.y; e[0][2] += w.x*v.z; e[0][3] += w.x*v.w;
        e[1][0] += w.y*v.x; e[1][1] += w.y*v.y; e[1][2] += w.y*v.z; e[1][3] += w.y*v.w;
        e[2][0] += w.z*v.x; e[2][1] += w.z*v.y; e[2][2] += w.z*v.z; e[2][3] += w.z*v.w;
        e[3][0] += w.w*v.x; e[3][1] += w.w*v.y; e[3][2] += w.w*v.z; e[3][3] += w.w*v.w;
      }
      if(j4 < lim){
        #pragma unroll
        for(int r = 0; r < 4; r++){
          int cl = clb + r;
          if(cl < 50){
            float bias = bg2p[cl];
            float4 o = make_float4(e[r][0]+bias, e[r][1]+bias, e[r][2]+bias, e[r][3]+bias);
            *(float4*)&ws[O_E2 + ((size_t)b*50 + cl)*4000 + nb + j4] = o;
          }
        }
      }
    }
  }
}

// ---------------- K4: reduce partials, divide by Z -> cluster_x ----------------
__global__ __launch_bounds__(256) void k_cxred(float* __restrict__ ws){
  int b = blockIdx.x, t = threadIdx.x;
  __shared__ float zi[64];
  if(t < 50){
    float s = 0.f;
    for(int ch = 0; ch < 8; ch++)
      s += ws[O_UCXP + ((size_t)(ch*64 + b)*132 + 128)*56 + t];
    zi[t] = 1.f / s;
  }
  __syncthreads();
  for(int i = t; i < 6400; i += 256){
    int d = i / 50, c = i % 50;
    float s = 0.f;
    for(int ch = 0; ch < 8; ch++)
      s += ws[O_UCXP + ((size_t)(ch*64 + b)*132 + d)*56 + c];
    ws[O_CX + (size_t)b*6400 + d*50 + c] = s * zi[c];
  }
}

// ---------------- K5: qkv + qkv1 projections (512x128 @ 128x50 per b) ----------------
__global__ __launch_bounds__(256) void k_qkv(const float* __restrict__ qw,
                                             const float* __restrict__ qb,
                                             const float* __restrict__ q1w,
                                             const float* __restrict__ q1b,
                                             float* __restrict__ ws){
  int rt = blockIdx.x, b = blockIdx.y;        // 8 row-tiles of 64
  __shared__ float wl[64*130];                // [rl][k] pad 130
  __shared__ float cxl[128*52];               // [k][c]
  int t = threadIdx.x;
  for(int i = t; i < 2048; i += 256){
    int rl = i >> 5, kq = i & 31, row = rt*64 + rl;
    float4 w = (row < 128) ? *(const float4*)&qw[row*128 + kq*4]
                           : *(const float4*)&q1w[(row-128)*128 + kq*4];
    int k0 = kq*4;
    wl[rl*130 + k0+0] = w.x; wl[rl*130 + k0+1] = w.y;
    wl[rl*130 + k0+2] = w.z; wl[rl*130 + k0+3] = w.w;
  }
  for(int i = t; i < 6656; i += 256){
    int k = i / 52, c = i % 52;
    cxl[i] = (c < 50) ? ws[O_CX + (size_t)b*6400 + k*50 + c] : 0.f;
  }
  __syncthreads();
  int ig = t & 15, cg = t >> 4;               // rows ig*4, cols cg*4 (cg<13)
  float acc[4][4];
  #pragma unroll
  for(int r = 0; r < 4; r++){ acc[r][0]=0.f; acc[r][1]=0.f; acc[r][2]=0.f; acc[r][3]=0.f; }
  if(cg < 13){
    int rb = ig*4, cb = cg*4;
    #pragma unroll 4
    for(int k = 0; k < 128; k++){
      float4 cv = *(const float4*)&cxl[k*52 + cb];
      float w0 = wl[(rb+0)*130 + k], w1 = wl[(rb+1)*130 + k];
      float w2 = wl[(rb+2)*130 + k], w3 = wl[(rb+3)*130 + k];
      acc[0][0] += w0*cv.x; acc[0][1] += w0*cv.y; acc[0][2] += w0*cv.z; acc[0][3] += w0*cv.w;
      acc[1][0] += w1*cv.x; acc[1][1] += w1*cv.y; acc[1][2] += w1*cv.z; acc[1][3] += w1*cv.w;
      acc[2][0] += w2*cv.x; acc[2][1] += w2*cv.y; acc[2][2] += w2*cv.z; acc[2][3] += w2*cv.w;
      acc[3][0] += w3*cv.x; acc[3][1] += w3*cv.y; acc[3][2] += w3*cv.z; acc[3][3] += w3*cv.w;
    }
    #pragma unroll
    for(int r = 0; r < 4; r++){
      int row = rt*64 + ig*4 + r;
      size_t base; float bias;
      if(row < 128){
        int h = row >> 5;
        bias = qb[row];
        base = O_XT + (size_t)(b*4 + h)*1600 + (row & 31);
      }else{
        int r2 = row - 128, h = r2/96, j = r2%96, kind = j >> 5, dd = j & 31;
        bias = q1b[r2];
        base = (kind==0 ? O_QT : kind==1 ? O_KT : O_VT) + (size_t)(b*4 + h)*1600 + dd;
      }
      #pragma unroll
      for(int s = 0; s < 4; s++){
        int c = cg*4 + s;
        if(c < 50) ws[base + (size_t)c*32] = acc[r][s] + bias;
      }
    }
  }
}

// ---------------- K6: knn (top-9, jax tie order) + edge + conv1 ----------------
__global__ __launch_bounds__(256) void k_knn(const float* __restrict__ g1w,
                                             const float* __restrict__ g1bias,
                                             float* __restrict__ ws){
  int h = blockIdx.x, b = blockIdx.y;
  __shared__ float xtl[50][33];
  __shared__ float pdl[50][52];
  __shared__ float sql[50];
  __shared__ int   idxl[50][9];
  __shared__ float w1l[6144];                 // [(i*3+t)*32+o]
  int t = threadIdx.x;
  const float* xtg = ws + O_XT + (size_t)(b*4 + h)*1600;
  for(int i = t; i < 1600; i += 256) xtl[i >> 5][i & 31] = xtg[i];
  for(int i = t; i < 6144; i += 256){
    int o = i / 192, r = i % 192, ii = r / 3, tt = r % 3;
    w1l[(ii*3 + tt)*32 + o] = g1w[(size_t)h*6144 + i];
  }
  __syncthreads();
  if(t < 50){
    float s = 0.f;
    for(int d = 0; d < 32; d++){ float v = xtl[t][d]; s += v*v; }
    sql[t] = s;
  }
  __syncthreads();
  for(int i = t; i < 2500; i += 256){
    int n = i / 50, m = i % 50;
    float s = 0.f;
    for(int d = 0; d < 32; d++) s += xtl[n][d]*xtl[m][d];
    pdl[n][m] = 2.f*s - sql[n] - sql[m];
  }
  __syncthreads();
  if(t < 50){
    float pv = INFINITY; int pi = -1;
    for(int k = 0; k < 9; k++){
      float bv = -INFINITY; int bi = 1000;
      for(int m = 0; m < 50; m++){
        float v = pdl[t][m];
        bool elig = (v < pv) || (v == pv && m > pi);
        if(elig && (v > bv || (v == bv && m < bi))){ bv = v; bi = m; }
      }
      idxl[t][k] = bi; pv = bv; pi = bi;
    }
  }
  __syncthreads();
  if(t < 150){
    int n = t / 3, jw = t % 3;
    float acc[32];
    #pragma unroll
    for(int o = 0; o < 32; o++) acc[o] = 0.f;
    for(int t3 = 0; t3 < 3; t3++){
      int kx = idxl[n][jw*3 + t3];
      for(int ii = 0; ii < 32; ii++){
        float c0 = xtl[n][ii];
        float c1 = c0 - xtl[kx][ii];
        const float* wr0 = w1l + (ii*3 + t3)*32;
        const float* wr1 = w1l + ((ii+32)*3 + t3)*32;
        #pragma unroll
        for(int o = 0; o < 32; o++) acc[o] += c0*wr0[o] + c1*wr1[o];
      }
    }
    float* out = ws + O_H1 + ((size_t)(b*4 + h)*150 + n*3 + jw)*32;
    #pragma unroll
    for(int o = 0; o < 32; o++) out[o] = acc[o] + g1bias[h*32 + o];
  }
}

// ---------------- K7: BN1 stats ----------------
__global__ void k_bn1p(float* __restrict__ ws){
  int b = blockIdx.x, t = threadIdx.x;
  int p = t & 127, half = t >> 7;
  int h = p >> 5, o = p & 31;
  const float* src = ws + O_H1 + (size_t)b*19200;
  float s = 0.f, sq = 0.f;
  for(int nj = half*75; nj < half*75 + 75; nj++){
    float v = src[(h*150 + nj)*32 + o];
    s += v; sq += v*v;
  }
  __shared__ float ls[256], lq[256];
  ls[t] = s; lq[t] = sq; __syncthreads();
  if(t < 128){
    ws[O_P1 + b*256 + p]       = ls[t] + ls[t+128];
    ws[O_P1 + b*256 + 128 + p] = lq[t] + lq[t+128];
  }
}

__global__ void k_bn1f(const float* g, const float* be, float* __restrict__ ws){
  int t = threadIdx.x;
  if(t < 128){
    float s = 0.f, sq = 0.f;
    for(int b = 0; b < 64; b++){ s += ws[O_P1 + b*256 + t]; sq += ws[O_P1 + b*256 + 128 + t]; }
    float mean = s * (1.f/9600.f), var = sq * (1.f/9600.f) - mean*mean;
    float sc = g[t] * rsqrtf(var + 1e-5f);
    ws[O_BN1S+t] = sc; ws[O_BN1T+t] = be[t] - sc*mean;
  }
}

// ---------------- K8: BN1+relu then conv2 (1x3) + BN2 partials ----------------
__global__ __launch_bounds__(256) void k_conv2(const float* __restrict__ g2w,
                                               const float* __restrict__ g2bias,
                                               float* __restrict__ ws){
  int h = blockIdx.x, b = blockIdx.y;
  __shared__ float hl[150][33];
  __shared__ float w2l[3072];
  __shared__ float rs[8][32], rq[8][32];
  int t = threadIdx.x;
  const float* h1p = ws + O_H1 + (size_t)(b*4 + h)*4800;
  for(int i = t; i < 4800; i += 256){
    int nj = i >> 5, ii = i & 31;
    hl[nj][ii] = fmaxf(ws[O_BN1S + h*32 + ii]*h1p[i] + ws[O_BN1T + h*32 + ii], 0.f);
  }
  for(int i = t; i < 3072; i += 256){
    int o = i / 96, r = i % 96, ii = r / 3, tt = r % 3;
    w2l[(ii*3 + tt)*32 + o] = g2w[(size_t)h*3072 + i];
  }
  __syncthreads();
  int o = t & 31, ng = t >> 5;
  float bias = g2bias[h*32 + o];
  float s = 0.f, sq = 0.f;
  for(int n = ng; n < 50; n += 8){
    float acc = 0.f;
    for(int t3 = 0; t3 < 3; t3++){
      const float* hr = hl[n*3 + t3];
      #pragma unroll
      for(int ii = 0; ii < 32; ii++) acc += hr[ii] * w2l[(ii*3 + t3)*32 + o];
    }
    acc += bias;
    ws[O_H2 + ((size_t)(b*4 + h)*50 + n)*32 + o] = acc;
    s += acc; sq += acc*acc;
  }
  rs[ng][o] = s; rq[ng][o] = sq; __syncthreads();
  if(t < 32){
    float S = 0.f, Q = 0.f;
    for(int g2 = 0; g2 < 8; g2++){ S += rs[g2][t]; Q += rq[g2][t]; }
    ws[O_P2 + (b*4 + h)*64 + t]      = S;
    ws[O_P2 + (b*4 + h)*64 + 32 + t] = Q;
  }
}

__global__ void k_bn2f(const float* g, const float* be, float* __restrict__ ws){
  int t = threadIdx.x;
  if(t < 128){
    int h = t >> 5, o = t & 31;
    float s = 0.f, sq = 0.f;
    for(int b = 0; b < 64; b++){
      s  += ws[O_P2 + (size_t)(b*4 + h)*64 + o];
      sq += ws[O_P2 + (size_t)(b*4 + h)*64 + 32 + o];
    }
    float mean = s * (1.f/3200.f), var = sq * (1.f/3200.f) - mean*mean;
    float sc = g[t] * rsqrtf(var + 1e-5f);
    ws[O_BN2S+t] = sc; ws[O_BN2T+t] = be[t] - sc*mean;
  }
}

// ---------------- K9: tiny attention + assemble cat [b][256][50] ----------------
__global__ __launch_bounds__(256) void k_attn(float* __restrict__ ws){
  int h = blockIdx.x, b = blockIdx.y;
  __shared__ float qtl[50][33], ktl[50][33], vtl[50][33], al[50][52];
  int t = threadIdx.x;
  size_t base = (size_t)(b*4 + h)*1600;
  for(int i = t; i < 1600; i += 256){
    int n = i >> 5, d = i & 31;
    qtl[n][d] = ws[O_QT + base + i];
    ktl[n][d] = ws[O_KT + base + i];
    vtl[n][d] = ws[O_VT + base + i];
  }
  __syncthreads();
  for(int i = t; i < 2500; i += 256){
    int n = i / 50, m = i % 50;
    float s = 0.f;
    for(int d = 0; d < 32; d++) s += qtl[n][d]*ktl[m][d];
    al[n][m] = s * 0.17677669529663687f;
  }
  __syncthreads();
  if(t < 50){
    float m = -INFINITY;
    for(int j = 0; j < 50; j++) m = fmaxf(m, al[t][j]);
    float s = 0.f;
    for(int j = 0; j < 50; j++){ float e = expf(al[t][j] - m); al[t][j] = e; s += e; }
    float inv = 1.f/s;
    for(int j = 0; j < 50; j++) al[t][j] *= inv;
  }
  __syncthreads();
  for(int i = t; i < 1600; i += 256){
    int n = i >> 5, d = i & 31;
    float gacc = 0.f;
    for(int m = 0; m < 50; m++) gacc += al[n][m]*vtl[m][d];
    ws[O_CAT + ((size_t)b*256 + h*64 + 32 + d)*50 + n] = gacc;
    float l = fmaxf(ws[O_BN2S + h*32 + d]*ws[O_H2 + ((size_t)(b*4 + h)*50 + n)*32 + d] + ws[O_BN2T + h*32 + d], 0.f);
    ws[O_CAT + ((size_t)b*256 + h*64 + d)*50 + n] = l;
  }
}

// ---------------- K10: pres2[b][c][o] = (M @ cat)[o][c] + vproj[o] ----------------
__global__ __launch_bounds__(256) void k_res(float* __restrict__ ws){
  int b = blockIdx.x;
  __shared__ float mtl[64*132];    // [k][o] pad 132
  __shared__ float catl[64*52];    // [k][c]
  __shared__ float vp[128];
  int t = threadIdx.x;
  if(t < 128) vp[t] = ws[O_VPROJ + t];
  int og = t >> 4, cg = t & 15;    // ob = og*8 (128 o), cb = cg*4 (cg<13)
  int ob = og*8, cb = cg*4;
  float acc[8][4];
  #pragma unroll
  for(int r = 0; r < 8; r++){ acc[r][0]=0.f; acc[r][1]=0.f; acc[r][2]=0.f; acc[r][3]=0.f; }
  for(int kc = 0; kc < 4; kc++){
    int k0 = kc*64;
    __syncthreads();
    for(int i = t; i < 2048; i += 256){
      int k = i >> 5, oq = i & 31;
      float4 m = *(const float4*)&ws[O_MT + (size_t)(k0 + k)*128 + oq*4];
      *(float4*)&mtl[k*132 + oq*4] = m;
    }
    for(int i = t; i < 3328; i += 256){
      int k = i / 52, c = i % 52;
      catl[i] = (c < 50) ? ws[O_CAT + (size_t)b*12800 + (k0 + k)*50 + c] : 0.f;
    }
    __syncthreads();
    if(cg < 13){
      #pragma unroll 2
      for(int k = 0; k < 64; k++){
        float4 m0 = *(const float4*)&mtl[k*132 + ob];
        float4 m1 = *(const float4*)&mtl[k*132 + ob + 4];
        float4 cv = *(const float4*)&catl[k*52 + cb];
        acc[0][0] += m0.x*cv.x; acc[0][1] += m0.x*cv.y; acc[0][2] += m0.x*cv.z; acc[0][3] += m0.x*cv.w;
        acc[1][0] += m0.y*cv.x; acc[1][1] += m0.y*cv.y; acc[1][2] += m0.y*cv.z; acc[1][3] += m0.y*cv.w;
        acc[2][0] += m0.z*cv.x; acc[2][1] += m0.z*cv.y; acc[2][2] += m0.z*cv.z; acc[2][3] += m0.z*cv.w;
        acc[3][0] += m0.w*cv.x; acc[3][1] += m0.w*cv.y; acc[3][2] += m0.w*cv.z; acc[3][3] += m0.w*cv.w;
        acc[4][0] += m1.x*cv.x; acc[4][1] += m1.x*cv.y; acc[4][2] += m1.x*cv.z; acc[4][3] += m1.x*cv.w;
        acc[5][0] += m1.y*cv.x; acc[5][1] += m1.y*cv.y; acc[5][2] += m1.y*cv.z; acc[5][3] += m1.y*cv.w;
        acc[6][0] += m1.z*cv.x; acc[6][1] += m1.z*cv.y; acc[6][2] += m1.z*cv.z; acc[6][3] += m1.z*cv.w;
        acc[7][0] += m1.w*cv.x; acc[7][1] += m1.w*cv.y; acc[7][2] += m1.w*cv.z; acc[7][3] += m1.w*cv.w;
      }
    }
  }
  if(cg < 13){
    #pragma unroll
    for(int s = 0; s < 4; s++){
      int c = cb + s;
      if(c < 50){
        float4 o0 = make_float4(acc[0][s]+vp[ob+0], acc[1][s]+vp[ob+1], acc[2][s]+vp[ob+2], acc[3][s]+vp[ob+3]);
        float4 o1 = make_float4(acc[4][s]+vp[ob+4], acc[5][s]+vp[ob+5], acc[6][s]+vp[ob+6], acc[7][s]+vp[ob+7]);
        *(float4*)&ws[O_PRES2 + (size_t)b*6400 + c*128 + ob]     = o0;
        *(float4*)&ws[O_PRES2 + (size_t)b*6400 + c*128 + ob + 4] = o1;
      }
    }
  }
}

// ---------------- K11: out = pres2 @ softmax_cl(embed2) + proj_b ----------------
__global__ __launch_bounds__(256) void k_out(const float* __restrict__ projb,
                                             float* __restrict__ ws,
                                             float* __restrict__ out){
  int nt = blockIdx.x, b = blockIdx.y;
  int n0 = nt*64;
  __shared__ float sl[50*64];      // [c][j]
  __shared__ float p2l[50*132];    // [c][o] pad 132
  __shared__ float pb[128];
  int t = threadIdx.x;
  for(int i = t; i < 3200; i += 256){
    int c = i >> 6, j = i & 63, n = n0 + j;
    sl[i] = (n < 4000) ? ws[O_E2 + ((size_t)b*50 + c)*4000 + n] : 0.f;
  }
  for(int i = t; i < 6400; i += 256){
    int c = i >> 7, o = i & 127;
    p2l[c*132 + o] = ws[O_PRES2 + (size_t)b*6400 + c*128 + o];
  }
  if(t < 128) pb[t] = projb[t];
  __syncthreads();
  if(t < 64){
    int j = t;
    float m = -INFINITY;
    for(int c = 0; c < 50; c++) m = fmaxf(m, sl[c*64 + j]);
    float s = 0.f;
    for(int c = 0; c < 50; c++){ float e = expf(sl[c*64 + j] - m); sl[c*64 + j] = e; s += e; }
    float inv = 1.f/s;
    for(int c = 0; c < 50; c++) sl[c*64 + j] *= inv;
  }
  __syncthreads();
  int og = t >> 4, jg = t & 15;
  int ob = og*8, j4 = jg*4;
  float acc[8][4];
  #pragma unroll
  for(int r = 0; r < 8; r++){ acc[r][0]=0.f; acc[r][1]=0.f; acc[r][2]=0.f; acc[r][3]=0.f; }
  #pragma unroll 2
  for(int c = 0; c < 50; c++){
    float4 sv = *(const float4*)&sl[c*64 + j4];
    float4 p0 = *(const float4*)&p2l[c*132 + ob];
    float4 p1 = *(const float4*)&p2l[c*132 + ob + 4];
    acc[0][0] += p0.x*sv.x; acc[0][1] += p0.x*sv.y; acc[0][2] += p0.x*sv.z; acc[0][3] += p0.x*sv.w;
    acc[1][0] += p0.y*sv.x; acc[1][1] += p0.y*sv.y; acc[1][2] += p0.y*sv.z; acc[1][3] += p0.y*sv.w;
    acc[2][0] += p0.z*sv.x; acc[2][1] += p0.z*sv.y; acc[2][2] += p0.z*sv.z; acc[2][3] += p0.z*sv.w;
    acc[3][0] += p0.w*sv.x; acc[3][1] += p0.w*sv.y; acc[3][2] += p0.w*sv.z; acc[3][3] += p0.w*sv.w;
    acc[4][0] += p1.x*sv.x; acc[4][1] += p1.x*sv.y; acc[4][2] += p1.x*sv.z; acc[4][3] += p1.x*sv.w;
    acc[5][0] += p1.y*sv.x; acc[5][1] += p1.y*sv.y; acc[5][2] += p1.y*sv.z; acc[5][3] += p1.y*sv.w;
    acc[6][0] += p1.z*sv.x; acc[6][1] += p1.z*sv.y; acc[6][2] += p1.z*sv.z; acc[6][3] += p1.z*sv.w;
    acc[7][0] += p1.w*sv.x; acc[7][1] += p1.w*sv.y; acc[7][2] += p1.w*sv.z; acc[7][3] += p1.w*sv.w;
  }
  int n = n0 + j4;
  if(n < 4000){
    #pragma unroll
    for(int r = 0; r < 8; r++){
      float bv = pb[ob + r];
      float4 o = make_float4(acc[r][0]+bv, acc[r][1]+bv, acc[r][2]+bv, acc[r][3]+bv);
      *(float4*)&out[(size_t)(b*128 + ob + r)*4000 + n] = o;
    }
  }
}

extern "C" void kernel_launch(void* const* d_in, const int* in_sizes, int n_in,
                              void* d_out, int out_size, void* d_ws, size_t ws_size,
                              hipStream_t stream){
  (void)in_sizes; (void)n_in; (void)out_size; (void)ws_size;
  const float* x      = (const float*)d_in[0];
  const float* wg1    = (const float*)d_in[1];
  const float* bg1    = (const float*)d_in[2];
  const float* g1g    = (const float*)d_in[3];
  const float* g1b    = (const float*)d_in[4];
  const float* wg2    = (const float*)d_in[5];
  const float* bg2    = (const float*)d_in[6];
  const float* g2g    = (const float*)d_in[7];
  const float* g2b    = (const float*)d_in[8];
  const float* qkvw   = (const float*)d_in[9];
  const float* qkvb   = (const float*)d_in[10];
  const float* qkv1w  = (const float*)d_in[11];
  const float* qkv1b  = (const float*)d_in[12];
  const float* gc1w   = (const float*)d_in[13];
  const float* gc1bias= (const float*)d_in[14];
  const float* gc1g   = (const float*)d_in[15];
  const float* gc1be  = (const float*)d_in[16];
  const float* gc2w   = (const float*)d_in[17];
  const float* gc2bias= (const float*)d_in[18];
  const float* gc2g   = (const float*)d_in[19];
  const float* gc2be  = (const float*)d_in[20];
  const float* presw  = (const float*)d_in[21];
  const float* presb  = (const float*)d_in[22];
  const float* projw  = (const float*)d_in[23];
  const float* projb  = (const float*)d_in[24];
  float* ws = (float*)d_ws;
  float* out = (float*)d_out;

  k_rowstats<<<8192, 256, 0, stream>>>(x, ws);
  k_prep<<<1, 256, 0, stream>>>(g1g, g1b, g2g, g2b, presb, projw, ws);
  k_mprep<<<128, 256, 0, stream>>>(presw, ws);
  k_e1ucx<<<dim3(8, 64), 256, 0, stream>>>(x, wg1, bg1, ws);
  k_e2<<<dim3(8, 64), 256, 0, stream>>>(x, wg2, bg2, ws);
  k_cxred<<<64, 256, 0, stream>>>(ws);
  k_qkv<<<dim3(8, 64), 256, 0, stream>>>(qkvw, qkvb, qkv1w, qkv1b, ws);
  k_knn<<<dim3(4, 64), 256, 0, stream>>>(gc1w, gc1bias, ws);
  k_bn1p<<<64, 256, 0, stream>>>(ws);
  k_bn1f<<<1, 128, 0, stream>>>(gc1g, gc1be, ws);
  k_conv2<<<dim3(4, 64), 256, 0, stream>>>(gc2w, gc2bias, ws);
  k_bn2f<<<1, 128, 0, stream>>>(gc2g, gc2be, ws);
  k_attn<<<dim3(4, 64), 256, 0, stream>>>(ws);
  k_res<<<64, 256, 0, stream>>>(ws);
  k_out<<<dim3(63, 64), 256, 0, stream>>>(projb, ws, out);
}

// Round 3
// 779.346 us; speedup vs baseline: 1.1107x; 1.0225x over previous
//
#include <hip/hip_runtime.h>
#include <cstddef>

// EfficientAttention pipeline, MI355X. fp32 throughout.
// B=64, DIM=128, N=4000, H=4, DH=32, CL=50, K=9.
// R6: T14 reg-prefetch staging in k_e1ucx/k_e2; k_e2 retiled to 48 (3 blocks/CU);
// k_cxred folded into k_qkv; bn1f->k_conv2, bn2f->k_attn; k_prep spread over 64
// blocks; k_rowstats wave-per-row (no barriers); k_bn1p split per (h,b).

// ---- workspace offsets (in floats) ----
constexpr size_t O_MU    = 0;                   // 8192
constexpr size_t O_RINV  = 8192;                // 8192
constexpr size_t O_RATIO = 16384;               // 8192
constexpr size_t O_A1    = 24576;               // 128
constexpr size_t O_B1    = 24704;
constexpr size_t O_A2    = 24832;
constexpr size_t O_B2    = 24960;
constexpr size_t O_PROJWT= 25088;               // 128x128 proj_w^T [d][o]
constexpr size_t O_VPROJ = 41472;               // 128  projw@pres_b
constexpr size_t O_MT    = 41600;               // 256x128  M^T [k][o], M=projw@presw
constexpr size_t O_E2    = 74368;               // 64*50*4000
constexpr size_t O_UCXP  = 12874368;            // 8*64*132*56 fused GEMM partials
constexpr size_t O_XT    = 17068672;            // 64*4*50*32 [b][h][c][d]
constexpr size_t O_QT    = 17478272;
constexpr size_t O_KT    = 17887872;
constexpr size_t O_VT    = 18297472;
constexpr size_t O_H1    = 18707072;            // 64*4*150*32
constexpr size_t O_P1    = 19935872;            // 64*256
constexpr size_t O_H2    = 19952512;            // 64*4*50*32
constexpr size_t O_P2    = 20362112;            // 256*64
constexpr size_t O_CAT   = 20378752;            // 64*256*50 [b][ch][n]
constexpr size_t O_PRES2 = 21197952;            // 64*50*128 [b][c][o]

// ---------------- K1: per-(b,c) instance-norm stats, wave-per-row ----------------
__global__ __launch_bounds__(256) void k_rowstats(const float* __restrict__ x,
                                                  float* __restrict__ ws){
  int w = threadIdx.x >> 6, lane = threadIdx.x & 63;
  int row = blockIdx.x*4 + w;                 // 2048 blocks * 4 rows
  const float4* xr = (const float4*)(x + (size_t)row * 4000);
  float s = 0.f, sq = 0.f;
  for(int i = lane; i < 1000; i += 64){
    float4 v = xr[i];
    s  += v.x + v.y + v.z + v.w;
    sq += v.x*v.x + v.y*v.y + v.z*v.z + v.w*v.w;
  }
  for(int off = 32; off > 0; off >>= 1){
    s  += __shfl_down(s,  off, 64);
    sq += __shfl_down(sq, off, 64);
  }
  if(lane == 0){
    float mean = s * (1.f/4000.f);
    float var  = sq * (1.f/4000.f) - mean*mean;
    ws[O_MU   + row] = mean;
    ws[O_RINV + row] = rsqrtf(var + 1e-3f);
    ws[O_RATIO+ row] = var / (var + 1e-3f);
  }
}

// ---------------- K2: PROJWT transpose (spread) + BN affine prep ----------------
__global__ __launch_bounds__(256) void k_prep(const float* g1g, const float* g1b,
                       const float* g2g, const float* g2b,
                       const float* projw, float* __restrict__ ws){
  int t = threadIdx.x;
  int i = blockIdx.x*256 + t;                 // 64 blocks -> 16384
  { int o = i & 127, k = i >> 7; ws[O_PROJWT+i] = projw[o*128 + k]; }
  if(blockIdx.x == 0 && t < 128){
    float s = 0.f;
    for(int b = 0; b < 64; b++) s += ws[O_RATIO + b*128 + t];
    float var2 = s * (1.f/64.f);
    float inv2 = rsqrtf(var2 + 1e-5f);
    ws[O_A1+t] = g1g[t] * inv2;  ws[O_B1+t] = g1b[t];
    ws[O_A2+t] = g2g[t] * inv2;  ws[O_B2+t] = g2b[t];
  }
}

// ---------------- K2b: M^T[k][o] (blocks 0..127) + VPROJ (block 128) ----------------
__global__ __launch_bounds__(256) void k_mprep(const float* __restrict__ presw,
                                               const float* __restrict__ presb,
                                               float* __restrict__ ws){
  int t = threadIdx.x;
  if(blockIdx.x < 128){
    int kk2 = blockIdx.x * 2;
    __shared__ float pwc[2][128];
    { int which = t >> 7, d = t & 127; pwc[which][d] = presw[d*256 + kk2 + which]; }
    __syncthreads();
    int which = t >> 7, o = t & 127;
    float acc = 0.f;
    for(int d = 0; d < 128; d++) acc += ws[O_PROJWT + d*128 + o] * pwc[which][d];
    ws[O_MT + (size_t)(kk2 + which)*128 + o] = acc;
  }else{
    if(t < 128){
      float v = 0.f;
      for(int d = 0; d < 128; d++) v += ws[O_PROJWT + d*128 + t] * presb[d];
      ws[O_VPROJ + t] = v;
    }
  }
}

// ---------------- K3a: embed1 + exp + unnormalized cluster GEMM partials + Z ----------------
// grid (8 ch, 64 b), 256 thr, n-tile 48, 11 subtiles. LDS ~76 KB -> 2 blocks/CU.
// T14: next x-chunk prefetched into registers during E1/exp/UCX.
__global__ __launch_bounds__(256) void k_e1ucx(const float* __restrict__ x,
    const float* __restrict__ wg1, const float* __restrict__ bg1,
    float* __restrict__ ws){
  int ch = blockIdx.x, b = blockIdx.y;
  __shared__ float lW1[128*52];     // [c][cl], rows 50,51 zero
  __shared__ float lrv1[128*48];    // relu1 [c][n]; after E1: eU overlay [52][48]
  __shared__ float lxt [48*132];    // x^T [n][d], pad 132
  __shared__ float ca1[128], cb1[128];
  __shared__ float bg1p[56];
  int t = threadIdx.x;
  if(t < 128){
    float mu = ws[O_MU + b*128 + t], ri = ws[O_RINV + b*128 + t];
    float a1 = ws[O_A1+t]*ri;
    ca1[t] = a1; cb1[t] = ws[O_B1+t] - a1*mu;
  }
  if(t < 56) bg1p[t] = (t < 50) ? bg1[t] : 0.f;
  for(int i = t; i < 1664; i += 256){
    int cl = i >> 5, cq = i & 31;
    float4 w = (cl < 50) ? *(const float4*)&wg1[cl*128 + cq*4] : make_float4(0.f,0.f,0.f,0.f);
    int c0 = cq*4;
    lW1[(c0+0)*52+cl] = w.x; lW1[(c0+1)*52+cl] = w.y;
    lW1[(c0+2)*52+cl] = w.z; lW1[(c0+3)*52+cl] = w.w;
  }
  // UCX map: 224 active threads, tile 4d x 8c
  int dg = t & 31, cg = t >> 5;
  float ua[4][8];
  #pragma unroll
  for(int r = 0; r < 4; r++)
    #pragma unroll
    for(int i = 0; i < 8; i++) ua[r][i] = 0.f;
  float zacc = 0.f;
  // E1 map: tile 4cl x 4n
  int ig = t >> 4, jg = t & 15;
  int clb = ig*4, j4 = jg*4;
  // stage mapping: 6 float4 per thread
  int sc[6], sj[6];
  float4 pf[6];
  #pragma unroll
  for(int j = 0; j < 6; j++){ int i = t + 256*j; sc[j] = i/12; sj[j] = (i%12)*4; }
  #pragma unroll
  for(int j = 0; j < 6; j++)
    pf[j] = *(const float4*)&x[(size_t)(b*128 + sc[j])*4000 + ch*500 + sj[j]];

  for(int st = 0; st < 11; st++){
    int lim = (st == 10) ? 20 : 48;
    __syncthreads();
    // stage from regs: lxt[n][d] raw (+zeros pad), lrv1 = relu(affine)
    #pragma unroll
    for(int j = 0; j < 6; j++){
      int c = sc[j], jj = sj[j];
      float4 xv = (jj < lim) ? pf[j] : make_float4(0.f,0.f,0.f,0.f);
      lxt[(jj+0)*132 + c] = xv.x; lxt[(jj+1)*132 + c] = xv.y;
      lxt[(jj+2)*132 + c] = xv.z; lxt[(jj+3)*132 + c] = xv.w;
      float a1 = ca1[c], b1v = cb1[c];
      float4 r1;
      r1.x = fmaxf(a1*xv.x + b1v, 0.f); r1.y = fmaxf(a1*xv.y + b1v, 0.f);
      r1.z = fmaxf(a1*xv.z + b1v, 0.f); r1.w = fmaxf(a1*xv.w + b1v, 0.f);
      *(float4*)&lrv1[c*48 + jj] = r1;
    }
    __syncthreads();
    // prefetch next subtile (flies during E1/exp/UCX)
    if(st < 10){
      int lim2 = (st == 9) ? 20 : 48;
      int nb2 = ch*500 + (st+1)*48;
      #pragma unroll
      for(int j = 0; j < 6; j++)
        pf[j] = (sj[j] < lim2) ? *(const float4*)&x[(size_t)(b*128 + sc[j])*4000 + nb2 + sj[j]]
                               : make_float4(0.f,0.f,0.f,0.f);
    }
    // E1 GEMM: 52 rows x 48 cols
    float e[4][4];
    if(ig < 13 && jg < 12){
      #pragma unroll
      for(int r = 0; r < 4; r++){ e[r][0]=0.f; e[r][1]=0.f; e[r][2]=0.f; e[r][3]=0.f; }
      #pragma unroll 4
      for(int c = 0; c < 128; c++){
        float4 w = *(const float4*)&lW1[c*52 + clb];
        float4 v = *(const float4*)&lrv1[c*48 + j4];
        e[0][0] += w.x*v.x; e[0][1] += w.x*v.y; e[0][2] += w.x*v.z; e[0][3] += w.x*v.w;
        e[1][0] += w.y*v.x; e[1][1] += w.y*v.y; e[1][2] += w.y*v.z; e[1][3] += w.y*v.w;
        e[2][0] += w.z*v.x; e[2][1] += w.z*v.y; e[2][2] += w.z*v.z; e[2][3] += w.z*v.w;
        e[3][0] += w.w*v.x; e[3][1] += w.w*v.y; e[3][2] += w.w*v.z; e[3][3] += w.w*v.w;
      }
    }
    __syncthreads();                 // E1 reads of lrv1 done -> overlay eU
    if(ig < 13 && jg < 12){
      bool live = (j4 < lim);
      #pragma unroll
      for(int r = 0; r < 4; r++){
        float bias = bg1p[clb + r];
        float4 u = make_float4(0.f,0.f,0.f,0.f);
        if(live){
          u.x = expf(e[r][0] + bias); u.y = expf(e[r][1] + bias);
          u.z = expf(e[r][2] + bias); u.w = expf(e[r][3] + bias);
        }
        *(float4*)&lrv1[(clb + r)*48 + j4] = u;
      }
    }
    __syncthreads();
    // UCX accumulate: ua[d][c] += x[d][n]*eU[c][n]
    if(t < 224){
      int d4 = dg*4, c8 = cg*8;
      for(int n4 = 0; n4 < 12; n4++){
        int n0 = n4*4;
        float4 uv[8];
        #pragma unroll
        for(int i = 0; i < 8; i++) uv[i] = *(const float4*)&lrv1[(c8 + i)*48 + n0];
        {
          float4 xq = *(const float4*)&lxt[(n0+0)*132 + d4];
          #pragma unroll
          for(int i = 0; i < 8; i++){
            float u = uv[i].x;
            ua[0][i] += xq.x*u; ua[1][i] += xq.y*u; ua[2][i] += xq.z*u; ua[3][i] += xq.w*u;
          }
        }
        {
          float4 xq = *(const float4*)&lxt[(n0+1)*132 + d4];
          #pragma unroll
          for(int i = 0; i < 8; i++){
            float u = uv[i].y;
            ua[0][i] += xq.x*u; ua[1][i] += xq.y*u; ua[2][i] += xq.z*u; ua[3][i] += xq.w*u;
          }
        }
        {
          float4 xq = *(const float4*)&lxt[(n0+2)*132 + d4];
          #pragma unroll
          for(int i = 0; i < 8; i++){
            float u = uv[i].z;
            ua[0][i] += xq.x*u; ua[1][i] += xq.y*u; ua[2][i] += xq.z*u; ua[3][i] += xq.w*u;
          }
        }
        {
          float4 xq = *(const float4*)&lxt[(n0+3)*132 + d4];
          #pragma unroll
          for(int i = 0; i < 8; i++){
            float u = uv[i].w;
            ua[0][i] += xq.x*u; ua[1][i] += xq.y*u; ua[2][i] += xq.z*u; ua[3][i] += xq.w*u;
          }
        }
      }
    }
    // Z: row-sum of masked eU
    if(t < 52){
      float s = 0.f;
      #pragma unroll
      for(int k = 0; k < 12; k++){
        float4 u = *(const float4*)&lrv1[t*48 + k*4];
        s += u.x + u.y + u.z + u.w;
      }
      zacc += s;
    }
  }
  // write partials [ch][b][132][56]: rows 0..127 = UCX, row 128 = Z
  if(t < 224){
    int d4 = dg*4, c8 = cg*8;
    #pragma unroll
    for(int r = 0; r < 4; r++){
      size_t base = O_UCXP + ((size_t)(ch*64 + b)*132 + d4 + r)*56 + c8;
      *(float4*)&ws[base]     = make_float4(ua[r][0], ua[r][1], ua[r][2], ua[r][3]);
      *(float4*)&ws[base + 4] = make_float4(ua[r][4], ua[r][5], ua[r][6], ua[r][7]);
    }
  }
  if(t < 52) ws[O_UCXP + ((size_t)(ch*64 + b)*132 + 128)*56 + t] = zacc;
}

// ---------------- K3b: embed2 (pre-softmax logits) -> O_E2 ----------------
// grid (8 ch, 64 b), 256 thr, n-tile 48, 11 subtiles. LDS ~51.2 KB -> 3 blocks/CU.
__global__ __launch_bounds__(256) void k_e2(const float* __restrict__ x,
    const float* __restrict__ wg2, const float* __restrict__ bg2,
    float* __restrict__ ws){
  int ch = blockIdx.x, b = blockIdx.y;
  __shared__ float lW2[128*52];
  __shared__ float lrv2[128*48];
  __shared__ float ca2[128], cb2[128];
  __shared__ float bg2p[56];
  int t = threadIdx.x;
  if(t < 128){
    float mu = ws[O_MU + b*128 + t], ri = ws[O_RINV + b*128 + t];
    float a2 = ws[O_A2+t]*ri;
    ca2[t] = a2; cb2[t] = ws[O_B2+t] - a2*mu;
  }
  if(t < 56) bg2p[t] = (t < 50) ? bg2[t] : 0.f;
  for(int i = t; i < 1664; i += 256){
    int cl = i >> 5, cq = i & 31;
    float4 w = (cl < 50) ? *(const float4*)&wg2[cl*128 + cq*4] : make_float4(0.f,0.f,0.f,0.f);
    int c0 = cq*4;
    lW2[(c0+0)*52+cl] = w.x; lW2[(c0+1)*52+cl] = w.y;
    lW2[(c0+2)*52+cl] = w.z; lW2[(c0+3)*52+cl] = w.w;
  }
  int ig = t >> 4, jg = t & 15;
  int clb = ig*4, j4 = jg*4;
  int sc[6], sj[6];
  float4 pf[6];
  #pragma unroll
  for(int j = 0; j < 6; j++){ int i = t + 256*j; sc[j] = i/12; sj[j] = (i%12)*4; }
  #pragma unroll
  for(int j = 0; j < 6; j++)
    pf[j] = *(const float4*)&x[(size_t)(b*128 + sc[j])*4000 + ch*500 + sj[j]];

  for(int st = 0; st < 11; st++){
    int nb = ch*500 + st*48;
    int lim = (st == 10) ? 20 : 48;
    __syncthreads();
    #pragma unroll
    for(int j = 0; j < 6; j++){
      int c = sc[j], jj = sj[j];
      float4 xv = (jj < lim) ? pf[j] : make_float4(0.f,0.f,0.f,0.f);
      float a2 = ca2[c], b2v = cb2[c];
      float4 r2;
      r2.x = fmaxf(a2*xv.x + b2v, 0.f); r2.y = fmaxf(a2*xv.y + b2v, 0.f);
      r2.z = fmaxf(a2*xv.z + b2v, 0.f); r2.w = fmaxf(a2*xv.w + b2v, 0.f);
      *(float4*)&lrv2[c*48 + jj] = r2;
    }
    __syncthreads();
    if(st < 10){
      int lim2 = (st == 9) ? 20 : 48;
      int nb2 = ch*500 + (st+1)*48;
      #pragma unroll
      for(int j = 0; j < 6; j++)
        pf[j] = (sj[j] < lim2) ? *(const float4*)&x[(size_t)(b*128 + sc[j])*4000 + nb2 + sj[j]]
                               : make_float4(0.f,0.f,0.f,0.f);
    }
    if(ig < 13 && jg < 12){
      float e[4][4];
      #pragma unroll
      for(int r = 0; r < 4; r++){ e[r][0]=0.f; e[r][1]=0.f; e[r][2]=0.f; e[r][3]=0.f; }
      #pragma unroll 4
      for(int c = 0; c < 128; c++){
        float4 w = *(const float4*)&lW2[c*52 + clb];
        float4 v = *(const float4*)&lrv2[c*48 + j4];
        e[0][0] += w.x*v.x; e[0][1] += w.x*v.y; e[0][2] += w.x*v.z; e[0][3] += w.x*v.w;
        e[1][0] += w.y*v.x; e[1][1] += w.y*v.y; e[1][2] += w.y*v.z; e[1][3] += w.y*v.w;
        e[2][0] += w.z*v.x; e[2][1] += w.z*v.y; e[2][2] += w.z*v.z; e[2][3] += w.z*v.w;
        e[3][0] += w.w*v.x; e[3][1] += w.w*v.y; e[3][2] += w.w*v.z; e[3][3] += w.w*v.w;
      }
      if(j4 < lim){
        #pragma unroll
        for(int r = 0; r < 4; r++){
          int cl = clb + r;
          if(cl < 50){
            float bias = bg2p[cl];
            float4 o = make_float4(e[r][0]+bias, e[r][1]+bias, e[r][2]+bias, e[r][3]+bias);
            *(float4*)&ws[O_E2 + ((size_t)b*50 + cl)*4000 + nb + j4] = o;
          }
        }
      }
    }
  }
}

// ---------------- K5: qkv + qkv1 projections, cluster_x reduced on load ----------------
__global__ __launch_bounds__(256) void k_qkv(const float* __restrict__ qw,
                                             const float* __restrict__ qb,
                                             const float* __restrict__ q1w,
                                             const float* __restrict__ q1b,
                                             float* __restrict__ ws){
  int rt = blockIdx.x, b = blockIdx.y;        // 8 row-tiles of 64
  __shared__ float wl[64*130];                // [rl][k] pad 130
  __shared__ float cxl[128*52];               // [k][c]
  __shared__ float zi[52];
  int t = threadIdx.x;
  if(t < 52){
    float s = 0.f;
    if(t < 50){
      #pragma unroll
      for(int ch = 0; ch < 8; ch++)
        s += ws[O_UCXP + ((size_t)(ch*64 + b)*132 + 128)*56 + t];
      zi[t] = 1.f / s;
    }else zi[t] = 0.f;
  }
  for(int i = t; i < 2048; i += 256){
    int rl = i >> 5, kq = i & 31, row = rt*64 + rl;
    float4 w = (row < 128) ? *(const float4*)&qw[row*128 + kq*4]
                           : *(const float4*)&q1w[(row-128)*128 + kq*4];
    int k0 = kq*4;
    wl[rl*130 + k0+0] = w.x; wl[rl*130 + k0+1] = w.y;
    wl[rl*130 + k0+2] = w.z; wl[rl*130 + k0+3] = w.w;
  }
  __syncthreads();
  for(int i = t; i < 6656; i += 256){
    int k = i / 52, c = i % 52;
    float s = 0.f;
    size_t base = O_UCXP + ((size_t)b*132 + k)*56 + c;
    #pragma unroll
    for(int ch = 0; ch < 8; ch++) s += ws[base + (size_t)ch*64*132*56];
    cxl[i] = s * zi[c];
  }
  __syncthreads();
  int ig = t & 15, cg = t >> 4;
  float acc[4][4];
  #pragma unroll
  for(int r = 0; r < 4; r++){ acc[r][0]=0.f; acc[r][1]=0.f; acc[r][2]=0.f; acc[r][3]=0.f; }
  if(cg < 13){
    int rb = ig*4, cb = cg*4;
    #pragma unroll 4
    for(int k = 0; k < 128; k++){
      float4 cv = *(const float4*)&cxl[k*52 + cb];
      float w0 = wl[(rb+0)*130 + k], w1 = wl[(rb+1)*130 + k];
      float w2 = wl[(rb+2)*130 + k], w3 = wl[(rb+3)*130 + k];
      acc[0][0] += w0*cv.x; acc[0][1] += w0*cv.y; acc[0][2] += w0*cv.z; acc[0][3] += w0*cv.w;
      acc[1][0] += w1*cv.x; acc[1][1] += w1*cv.y; acc[1][2] += w1*cv.z; acc[1][3] += w1*cv.w;
      acc[2][0] += w2*cv.x; acc[2][1] += w2*cv.y; acc[2][2] += w2*cv.z; acc[2][3] += w2*cv.w;
      acc[3][0] += w3*cv.x; acc[3][1] += w3*cv.y; acc[3][2] += w3*cv.z; acc[3][3] += w3*cv.w;
    }
    #pragma unroll
    for(int r = 0; r < 4; r++){
      int row = rt*64 + ig*4 + r;
      size_t base; float bias;
      if(row < 128){
        int h = row >> 5;
        bias = qb[row];
        base = O_XT + (size_t)(b*4 + h)*1600 + (row & 31);
      }else{
        int r2 = row - 128, h = r2/96, j = r2%96, kind = j >> 5, dd = j & 31;
        bias = q1b[r2];
        base = (kind==0 ? O_QT : kind==1 ? O_KT : O_VT) + (size_t)(b*4 + h)*1600 + dd;
      }
      #pragma unroll
      for(int s = 0; s < 4; s++){
        int c = cg*4 + s;
        if(c < 50) ws[base + (size_t)c*32] = acc[r][s] + bias;
      }
    }
  }
}

// ---------------- K6: knn (top-9, jax tie order) + edge + conv1 ----------------
__global__ __launch_bounds__(256) void k_knn(const float* __restrict__ g1w,
                                             const float* __restrict__ g1bias,
                                             float* __restrict__ ws){
  int h = blockIdx.x, b = blockIdx.y;
  __shared__ float xtl[50][33];
  __shared__ float pdl[50][52];
  __shared__ float sql[50];
  __shared__ int   idxl[50][9];
  __shared__ float w1l[6144];                 // [(i*3+t)*32+o]
  int t = threadIdx.x;
  const float* xtg = ws + O_XT + (size_t)(b*4 + h)*1600;
  for(int i = t; i < 1600; i += 256) xtl[i >> 5][i & 31] = xtg[i];
  for(int i = t; i < 6144; i += 256){
    int o = i / 192, r = i % 192, ii = r / 3, tt = r % 3;
    w1l[(ii*3 + tt)*32 + o] = g1w[(size_t)h*6144 + i];
  }
  __syncthreads();
  if(t < 50){
    float s = 0.f;
    for(int d = 0; d < 32; d++){ float v = xtl[t][d]; s += v*v; }
    sql[t] = s;
  }
  __syncthreads();
  for(int i = t; i < 2500; i += 256){
    int n = i / 50, m = i % 50;
    float s = 0.f;
    for(int d = 0; d < 32; d++) s += xtl[n][d]*xtl[m][d];
    pdl[n][m] = 2.f*s - sql[n] - sql[m];
  }
  __syncthreads();
  if(t < 50){
    float pv = INFINITY; int pi = -1;
    for(int k = 0; k < 9; k++){
      float bv = -INFINITY; int bi = 1000;
      for(int m = 0; m < 50; m++){
        float v = pdl[t][m];
        bool elig = (v < pv) || (v == pv && m > pi);
        if(elig && (v > bv || (v == bv && m < bi))){ bv = v; bi = m; }
      }
      idxl[t][k] = bi; pv = bv; pi = bi;
    }
  }
  __syncthreads();
  if(t < 150){
    int n = t / 3, jw = t % 3;
    float acc[32];
    #pragma unroll
    for(int o = 0; o < 32; o++) acc[o] = 0.f;
    for(int t3 = 0; t3 < 3; t3++){
      int kx = idxl[n][jw*3 + t3];
      for(int ii = 0; ii < 32; ii++){
        float c0 = xtl[n][ii];
        float c1 = c0 - xtl[kx][ii];
        const float* wr0 = w1l + (ii*3 + t3)*32;
        const float* wr1 = w1l + ((ii+32)*3 + t3)*32;
        #pragma unroll
        for(int o = 0; o < 32; o++) acc[o] += c0*wr0[o] + c1*wr1[o];
      }
    }
    float* out = ws + O_H1 + ((size_t)(b*4 + h)*150 + n*3 + jw)*32;
    #pragma unroll
    for(int o = 0; o < 32; o++) out[o] = acc[o] + g1bias[h*32 + o];
  }
}

// ---------------- K7: BN1 partial sums per (h,b) ----------------
__global__ __launch_bounds__(256) void k_bn1p(float* __restrict__ ws){
  int h = blockIdx.x, b = blockIdx.y, t = threadIdx.x;
  int o = t & 31, part = t >> 5;
  const float* src = ws + O_H1 + (size_t)(b*4 + h)*4800;
  float s = 0.f, sq = 0.f;
  for(int nj = part; nj < 150; nj += 8){
    float v = src[nj*32 + o];
    s += v; sq += v*v;
  }
  __shared__ float rs[8][33], rq[8][33];
  rs[part][o] = s; rq[part][o] = sq; __syncthreads();
  if(t < 32){
    float S = 0.f, Q = 0.f;
    for(int p = 0; p < 8; p++){ S += rs[p][t]; Q += rq[p][t]; }
    ws[O_P1 + b*256 + h*32 + t]       = S;
    ws[O_P1 + b*256 + 128 + h*32 + t] = Q;
  }
}

// ---------------- K8: BN1(inline)+relu then conv2 (1x3) + BN2 partials ----------------
__global__ __launch_bounds__(256) void k_conv2(const float* __restrict__ g1g,
                                               const float* __restrict__ g1be,
                                               const float* __restrict__ g2w,
                                               const float* __restrict__ g2bias,
                                               float* __restrict__ ws){
  int h = blockIdx.x, b = blockIdx.y;
  __shared__ float hl[150][33];
  __shared__ float w2l[3072];
  __shared__ float rs[8][32], rq[8][32];
  __shared__ float b1s[32], b1t[32];
  int t = threadIdx.x;
  if(t < 32){
    float s = 0.f, sq = 0.f;
    for(int bb = 0; bb < 64; bb++){
      s  += ws[O_P1 + bb*256 + h*32 + t];
      sq += ws[O_P1 + bb*256 + 128 + h*32 + t];
    }
    float mean = s * (1.f/9600.f), var = sq * (1.f/9600.f) - mean*mean;
    float sc = g1g[h*32+t] * rsqrtf(var + 1e-5f);
    b1s[t] = sc; b1t[t] = g1be[h*32+t] - sc*mean;
  }
  for(int i = t; i < 3072; i += 256){
    int o = i / 96, r = i % 96, ii = r / 3, tt = r % 3;
    w2l[(ii*3 + tt)*32 + o] = g2w[(size_t)h*3072 + i];
  }
  __syncthreads();
  const float* h1p = ws + O_H1 + (size_t)(b*4 + h)*4800;
  for(int i = t; i < 4800; i += 256){
    int nj = i >> 5, ii = i & 31;
    hl[nj][ii] = fmaxf(b1s[ii]*h1p[i] + b1t[ii], 0.f);
  }
  __syncthreads();
  int o = t & 31, ng = t >> 5;
  float bias = g2bias[h*32 + o];
  float s = 0.f, sq = 0.f;
  for(int n = ng; n < 50; n += 8){
    float acc = 0.f;
    for(int t3 = 0; t3 < 3; t3++){
      const float* hr = hl[n*3 + t3];
      #pragma unroll
      for(int ii = 0; ii < 32; ii++) acc += hr[ii] * w2l[(ii*3 + t3)*32 + o];
    }
    acc += bias;
    ws[O_H2 + ((size_t)(b*4 + h)*50 + n)*32 + o] = acc;
    s += acc; sq += acc*acc;
  }
  rs[ng][o] = s; rq[ng][o] = sq; __syncthreads();
  if(t < 32){
    float S = 0.f, Q = 0.f;
    for(int g2 = 0; g2 < 8; g2++){ S += rs[g2][t]; Q += rq[g2][t]; }
    ws[O_P2 + (b*4 + h)*64 + t]      = S;
    ws[O_P2 + (b*4 + h)*64 + 32 + t] = Q;
  }
}

// ---------------- K9: BN2(inline) + tiny attention + assemble cat ----------------
__global__ __launch_bounds__(256) void k_attn(const float* __restrict__ g2g,
                                              const float* __restrict__ g2be,
                                              float* __restrict__ ws){
  int h = blockIdx.x, b = blockIdx.y;
  __shared__ float qtl[50][33], ktl[50][33], vtl[50][33], al[50][52];
  __shared__ float b2s[32], b2t[32];
  int t = threadIdx.x;
  if(t < 32){
    float s = 0.f, sq = 0.f;
    for(int bb = 0; bb < 64; bb++){
      s  += ws[O_P2 + (size_t)(bb*4 + h)*64 + t];
      sq += ws[O_P2 + (size_t)(bb*4 + h)*64 + 32 + t];
    }
    float mean = s * (1.f/3200.f), var = sq * (1.f/3200.f) - mean*mean;
    float sc = g2g[h*32+t] * rsqrtf(var + 1e-5f);
    b2s[t] = sc; b2t[t] = g2be[h*32+t] - sc*mean;
  }
  size_t base = (size_t)(b*4 + h)*1600;
  for(int i = t; i < 1600; i += 256){
    int n = i >> 5, d = i & 31;
    qtl[n][d] = ws[O_QT + base + i];
    ktl[n][d] = ws[O_KT + base + i];
    vtl[n][d] = ws[O_VT + base + i];
  }
  __syncthreads();
  for(int i = t; i < 2500; i += 256){
    int n = i / 50, m = i % 50;
    float s = 0.f;
    for(int d = 0; d < 32; d++) s += qtl[n][d]*ktl[m][d];
    al[n][m] = s * 0.17677669529663687f;
  }
  __syncthreads();
  if(t < 50){
    float m = -INFINITY;
    for(int j = 0; j < 50; j++) m = fmaxf(m, al[t][j]);
    float s = 0.f;
    for(int j = 0; j < 50; j++){ float e = expf(al[t][j] - m); al[t][j] = e; s += e; }
    float inv = 1.f/s;
    for(int j = 0; j < 50; j++) al[t][j] *= inv;
  }
  __syncthreads();
  for(int i = t; i < 1600; i += 256){
    int n = i >> 5, d = i & 31;
    float gacc = 0.f;
    for(int m = 0; m < 50; m++) gacc += al[n][m]*vtl[m][d];
    ws[O_CAT + ((size_t)b*256 + h*64 + 32 + d)*50 + n] = gacc;
    float l = fmaxf(b2s[d]*ws[O_H2 + ((size_t)(b*4 + h)*50 + n)*32 + d] + b2t[d], 0.f);
    ws[O_CAT + ((size_t)b*256 + h*64 + d)*50 + n] = l;
  }
}

// ---------------- K10: pres2[b][c][o] = (M @ cat)[o][c] + vproj[o] ----------------
__global__ __launch_bounds__(256) void k_res(float* __restrict__ ws){
  int b = blockIdx.x;
  __shared__ float mtl[64*132];    // [k][o] pad 132
  __shared__ float catl[64*52];    // [k][c]
  __shared__ float vp[128];
  int t = threadIdx.x;
  if(t < 128) vp[t] = ws[O_VPROJ + t];
  int og = t >> 4, cg = t & 15;
  int ob = og*8, cb = cg*4;
  float acc[8][4];
  #pragma unroll
  for(int r = 0; r < 8; r++){ acc[r][0]=0.f; acc[r][1]=0.f; acc[r][2]=0.f; acc[r][3]=0.f; }
  for(int kc = 0; kc < 4; kc++){
    int k0 = kc*64;
    __syncthreads();
    for(int i = t; i < 2048; i += 256){
      int k = i >> 5, oq = i & 31;
      float4 m = *(const float4*)&ws[O_MT + (size_t)(k0 + k)*128 + oq*4];
      *(float4*)&mtl[k*132 + oq*4] = m;
    }
    for(int i = t; i < 3328; i += 256){
      int k = i / 52, c = i % 52;
      catl[i] = (c < 50) ? ws[O_CAT + (size_t)b*12800 + (k0 + k)*50 + c] : 0.f;
    }
    __syncthreads();
    if(cg < 13){
      #pragma unroll 2
      for(int k = 0; k < 64; k++){
        float4 m0 = *(const float4*)&mtl[k*132 + ob];
        float4 m1 = *(const float4*)&mtl[k*132 + ob + 4];
        float4 cv = *(const float4*)&catl[k*52 + cb];
        acc[0][0] += m0.x*cv.x; acc[0][1] += m0.x*cv.y; acc[0][2] += m0.x*cv.z; acc[0][3] += m0.x*cv.w;
        acc[1][0] += m0.y*cv.x; acc[1][1] += m0.y*cv.y; acc[1][2] += m0.y*cv.z; acc[1][3] += m0.y*cv.w;
        acc[2][0] += m0.z*cv.x; acc[2][1] += m0.z*cv.y; acc[2][2] += m0.z*cv.z; acc[2][3] += m0.z*cv.w;
        acc[3][0] += m0.w*cv.x; acc[3][1] += m0.w*cv.y; acc[3][2] += m0.w*cv.z; acc[3][3] += m0.w*cv.w;
        acc[4][0] += m1.x*cv.x; acc[4][1] += m1.x*cv.y; acc[4][2] += m1.x*cv.z; acc[4][3] += m1.x*cv.w;
        acc[5][0] += m1.y*cv.x; acc[5][1] += m1.y*cv.y; acc[5][2] += m1.y*cv.z; acc[5][3] += m1.y*cv.w;
        acc[6][0] += m1.z*cv.x; acc[6][1] += m1.z*cv.y; acc[6][2] += m1.z*cv.z; acc[6][3] += m1.z*cv.w;
        acc[7][0] += m1.w*cv.x; acc[7][1] += m1.w*cv.y; acc[7][2] += m1.w*cv.z; acc[7][3] += m1.w*cv.w;
      }
    }
  }
  if(cg < 13){
    #pragma unroll
    for(int s = 0; s < 4; s++){
      int c = cb + s;
      if(c < 50){
        float4 o0 = make_float4(acc[0][s]+vp[ob+0], acc[1][s]+vp[ob+1], acc[2][s]+vp[ob+2], acc[3][s]+vp[ob+3]);
        float4 o1 = make_float4(acc[4][s]+vp[ob+4], acc[5][s]+vp[ob+5], acc[6][s]+vp[ob+6], acc[7][s]+vp[ob+7]);
        *(float4*)&ws[O_PRES2 + (size_t)b*6400 + c*128 + ob]     = o0;
        *(float4*)&ws[O_PRES2 + (size_t)b*6400 + c*128 + ob + 4] = o1;
      }
    }
  }
}

// ---------------- K11: out = pres2 @ softmax_cl(embed2) + proj_b ----------------
__global__ __launch_bounds__(256) void k_out(const float* __restrict__ projb,
                                             float* __restrict__ ws,
                                             float* __restrict__ out){
  int nt = blockIdx.x, b = blockIdx.y;
  int n0 = nt*64;
  __shared__ float sl[50*64];      // [c][j]
  __shared__ float p2l[50*132];    // [c][o] pad 132
  __shared__ float pb[128];
  int t = threadIdx.x;
  for(int i = t; i < 3200; i += 256){
    int c = i >> 6, j = i & 63, n = n0 + j;
    sl[i] = (n < 4000) ? ws[O_E2 + ((size_t)b*50 + c)*4000 + n] : 0.f;
  }
  for(int i = t; i < 6400; i += 256){
    int c = i >> 7, o = i & 127;
    p2l[c*132 + o] = ws[O_PRES2 + (size_t)b*6400 + c*128 + o];
  }
  if(t < 128) pb[t] = projb[t];
  __syncthreads();
  if(t < 64){
    int j = t;
    float m = -INFINITY;
    for(int c = 0; c < 50; c++) m = fmaxf(m, sl[c*64 + j]);
    float s = 0.f;
    for(int c = 0; c < 50; c++){ float e = expf(sl[c*64 + j] - m); sl[c*64 + j] = e; s += e; }
    float inv = 1.f/s;
    for(int c = 0; c < 50; c++) sl[c*64 + j] *= inv;
  }
  __syncthreads();
  int og = t >> 4, jg = t & 15;
  int ob = og*8, j4 = jg*4;
  float acc[8][4];
  #pragma unroll
  for(int r = 0; r < 8; r++){ acc[r][0]=0.f; acc[r][1]=0.f; acc[r][2]=0.f; acc[r][3]=0.f; }
  #pragma unroll 2
  for(int c = 0; c < 50; c++){
    float4 sv = *(const float4*)&sl[c*64 + j4];
    float4 p0 = *(const float4*)&p2l[c*132 + ob];
    float4 p1 = *(const float4*)&p2l[c*132 + ob + 4];
    acc[0][0] += p0.x*sv.x; acc[0][1] += p0.x*sv.y; acc[0][2] += p0.x*sv.z; acc[0][3] += p0.x*sv.w;
    acc[1][0] += p0.y*sv.x; acc[1][1] += p0.y*sv.y; acc[1][2] += p0.y*sv.z; acc[1][3] += p0.y*sv.w;
    acc[2][0] += p0.z*sv.x; acc[2][1] += p0.z*sv.y; acc[2][2] += p0.z*sv.z; acc[2][3] += p0.z*sv.w;
    acc[3][0] += p0.w*sv.x; acc[3][1] += p0.w*sv.y; acc[3][2] += p0.w*sv.z; acc[3][3] += p0.w*sv.w;
    acc[4][0] += p1.x*sv.x; acc[4][1] += p1.x*sv.y; acc[4][2] += p1.x*sv.z; acc[4][3] += p1.x*sv.w;
    acc[5][0] += p1.y*sv.x; acc[5][1] += p1.y*sv.y; acc[5][2] += p1.y*sv.z; acc[5][3] += p1.y*sv.w;
    acc[6][0] += p1.z*sv.x; acc[6][1] += p1.z*sv.y; acc[6][2] += p1.z*sv.z; acc[6][3] += p1.z*sv.w;
    acc[7][0] += p1.w*sv.x; acc[7][1] += p1.w*sv.y; acc[7][2] += p1.w*sv.z; acc[7][3] += p1.w*sv.w;
  }
  int n = n0 + j4;
  if(n < 4000){
    #pragma unroll
    for(int r = 0; r < 8; r++){
      float bv = pb[ob + r];
      float4 o = make_float4(acc[r][0]+bv, acc[r][1]+bv, acc[r][2]+bv, acc[r][3]+bv);
      *(float4*)&out[(size_t)(b*128 + ob + r)*4000 + n] = o;
    }
  }
}

extern "C" void kernel_launch(void* const* d_in, const int* in_sizes, int n_in,
                              void* d_out, int out_size, void* d_ws, size_t ws_size,
                              hipStream_t stream){
  (void)in_sizes; (void)n_in; (void)out_size; (void)ws_size;
  const float* x      = (const float*)d_in[0];
  const float* wg1    = (const float*)d_in[1];
  const float* bg1    = (const float*)d_in[2];
  const float* g1g    = (const float*)d_in[3];
  const float* g1b    = (const float*)d_in[4];
  const float* wg2    = (const float*)d_in[5];
  const float* bg2    = (const float*)d_in[6];
  const float* g2g    = (const float*)d_in[7];
  const float* g2b    = (const float*)d_in[8];
  const float* qkvw   = (const float*)d_in[9];
  const float* qkvb   = (const float*)d_in[10];
  const float* qkv1w  = (const float*)d_in[11];
  const float* qkv1b  = (const float*)d_in[12];
  const float* gc1w   = (const float*)d_in[13];
  const float* gc1bias= (const float*)d_in[14];
  const float* gc1g   = (const float*)d_in[15];
  const float* gc1be  = (const float*)d_in[16];
  const float* gc2w   = (const float*)d_in[17];
  const float* gc2bias= (const float*)d_in[18];
  const float* gc2g   = (const float*)d_in[19];
  const float* gc2be  = (const float*)d_in[20];
  const float* presw  = (const float*)d_in[21];
  const float* presb  = (const float*)d_in[22];
  const float* projw  = (const float*)d_in[23];
  const float* projb  = (const float*)d_in[24];
  float* ws = (float*)d_ws;
  float* out = (float*)d_out;

  k_rowstats<<<2048, 256, 0, stream>>>(x, ws);
  k_prep<<<64, 256, 0, stream>>>(g1g, g1b, g2g, g2b, projw, ws);
  k_mprep<<<129, 256, 0, stream>>>(presw, presb, ws);
  k_e1ucx<<<dim3(8, 64), 256, 0, stream>>>(x, wg1, bg1, ws);
  k_e2<<<dim3(8, 64), 256, 0, stream>>>(x, wg2, bg2, ws);
  k_qkv<<<dim3(8, 64), 256, 0, stream>>>(qkvw, qkvb, qkv1w, qkv1b, ws);
  k_knn<<<dim3(4, 64), 256, 0, stream>>>(gc1w, gc1bias, ws);
  k_bn1p<<<dim3(4, 64), 256, 0, stream>>>(ws);
  k_conv2<<<dim3(4, 64), 256, 0, stream>>>(gc1g, gc1be, gc2w, gc2bias, ws);
  k_attn<<<dim3(4, 64), 256, 0, stream>>>(gc2g, gc2be, ws);
  k_res<<<64, 256, 0, stream>>>(ws);
  k_out<<<dim3(63, 64), 256, 0, stream>>>(projb, ws, out);
}